// Round 1
// baseline (735.467 us; speedup 1.0000x reference)
//
#include <hip/hip_runtime.h>
#include <hip/hip_fp16.h>

namespace {

constexpr int kUsers = 100000;
constexpr int kItems = 200000;
constexpr int kN     = kUsers + kItems;   // 300000
constexpr int kD     = 64;
constexpr int kNNZ   = 5000000;
constexpr int kB     = 16384;
constexpr int kRowsPerBkt = 2048;                       // rows per coarse bucket
constexpr int kNBKT  = (kN + kRowsPerBkt - 1) / kRowsPerBkt;  // 147
constexpr int kSEPB  = 4096;                            // edges per bucket_scatter block
constexpr int kCE    = 8192;                            // edges per finalize chunk
constexpr int kMC    = 5;                               // chunks per bucket
constexpr int kCap   = kMC * kCE;                       // 40960 slots/bucket (mean 34133, sd 185)
constexpr int kMaxSub = 2 * kB;                         // upper bound on marked rows

typedef int   v2i __attribute__((ext_vector_type(2)));
typedef int   v4i __attribute__((ext_vector_type(4)));
typedef float v4f __attribute__((ext_vector_type(4)));

__global__ void zero_i32(int* __restrict__ p, int n) {
  int i = blockIdx.x * blockDim.x + threadIdx.x;
  if (i < n) p[i] = 0;
}

// Counting-sort partition of 4096 edges into 147 coarse buckets; per-wave LDS
// histograms (4x147) cut same-address atomic serialization 4x. LDS staging so
// tmp writes go out in coalesced bucket-run bursts. Streaming in/out marked
// nontemporal: every byte touched exactly once, keep L2 for later consumers.
__global__ void bucket_scatter(const int* __restrict__ row, const int* __restrict__ col,
                               const float* __restrict__ val, int* __restrict__ gpos,
                               int2* __restrict__ tmp) {
  __shared__ int hcnt[4][kNBKT];   // per-wave counts -> wave-exclusive offsets
  __shared__ int lofs[kNBKT];
  __shared__ int hbase[kNBKT];
  __shared__ int lds[256];
  __shared__ int2 se[kSEPB];
  __shared__ unsigned short sb[kSEPB];
  int t = threadIdx.x;
  int wv = t >> 6;
  long base = (long)blockIdx.x * kSEPB;
  int valid = (int)min((long)kSEPB, (long)kNNZ - base);
  for (int i = t; i < kNBKT; i += 256) {
    hcnt[0][i] = 0; hcnt[1][i] = 0; hcnt[2][i] = 0; hcnt[3][i] = 0;
  }
  __syncthreads();
  int pk[16], bk[16], rk[16];
  float v[16];
  bool ok[16];
#pragma unroll
  for (int j = 0; j < 16; ++j) {
    long i = base + j * 256 + t;
    ok[j] = (i < kNNZ);
    if (ok[j]) {
      int r = __builtin_nontemporal_load(row + i);
      bk[j] = r >> 11;
      pk[j] = ((r & 2047) << 19) | __builtin_nontemporal_load(col + i);
      v[j] = __builtin_nontemporal_load(val + i);
      rk[j] = atomicAdd(&hcnt[wv][bk[j]], 1);
    }
  }
  __syncthreads();
  // per-bucket: wave-exclusive offsets + total; then block scan of totals
  int own = 0;
  if (t < kNBKT) {
    int c0 = hcnt[0][t], c1 = hcnt[1][t], c2 = hcnt[2][t], c3 = hcnt[3][t];
    hcnt[0][t] = 0; hcnt[1][t] = c0; hcnt[2][t] = c0 + c1; hcnt[3][t] = c0 + c1 + c2;
    own = c0 + c1 + c2 + c3;
  }
  lds[t] = own;
  __syncthreads();
  for (int o = 1; o < 256; o <<= 1) {
    int x = (t >= o) ? lds[t - o] : 0;
    __syncthreads();
    if (t >= o) lds[t] += x;
    __syncthreads();
  }
  if (t < kNBKT) {
    lofs[t] = lds[t] - own;
    hbase[t] = t * kCap + atomicAdd(&gpos[t], own);
  }
  __syncthreads();
  // place into LDS in bucket-sorted order
#pragma unroll
  for (int j = 0; j < 16; ++j) {
    if (ok[j]) {
      int pos = lofs[bk[j]] + hcnt[wv][bk[j]] + rk[j];
      se[pos] = make_int2(pk[j], __float_as_int(v[j]));
      sb[pos] = (unsigned short)bk[j];
    }
  }
  __syncthreads();
  // drain LDS sequentially -> coalesced global runs
#pragma unroll
  for (int j = 0; j < 16; ++j) {
    int pos = t + j * 256;
    if (pos < valid) {
      int b = sb[pos];
      int2 e2 = se[pos];
      v2i pk2; pk2.x = e2.x; pk2.y = e2.y;
      __builtin_nontemporal_store(pk2, (v2i*)(tmp + hbase[b] + (pos - lofs[b])));
    }
  }
}

// Grid = kNBKT*kMC. Per-(bucket,chunk) 2048-row LDS histogram -> ctab.
__global__ void chunk_hist(const int* __restrict__ gpos, const int2* __restrict__ tmp,
                           int* __restrict__ ctab) {
  __shared__ int h[kRowsPerBkt];
  int b = blockIdx.x / kMC, c = blockIdx.x % kMC;
  int t = threadIdx.x;
  for (int i = t; i < kRowsPerBkt; i += 256) h[i] = 0;
  __syncthreads();
  int s = b * kCap + c * kCE;
  int e = b * kCap + gpos[b];
  if (s + kCE < e) e = s + kCE;
  for (int j = s + t; j < e; j += 256)
    atomicAdd(&h[__builtin_nontemporal_load(&tmp[j].x) >> 19], 1);
  __syncthreads();
  int* dst = ctab + (size_t)blockIdx.x * kRowsPerBkt;
  for (int i = t; i < kRowsPerBkt; i += 256) dst[i] = h[i];
}

// Per-row totals over chunks (ctab -> chunk-exclusive prefixes), block-scan of
// 2048 row totals -> bucket-local rowptr + per-bucket partial.
__global__ void scanA(int* __restrict__ ctab, int* __restrict__ rowptr,
                      int* __restrict__ partials) {
  __shared__ int lsum[256];
  int b = blockIdx.x, t = threadIdx.x;
  int cnt[8];
#pragma unroll
  for (int k = 0; k < 8; ++k) cnt[k] = 0;
  for (int c = 0; c < kMC; ++c) {
    int* p = ctab + (size_t)(b * kMC + c) * kRowsPerBkt;
#pragma unroll
    for (int k = 0; k < 8; ++k) {
      int idx = t * 8 + k;
      int v = p[idx];
      p[idx] = cnt[k];
      cnt[k] += v;
    }
  }
  int s = 0, pref[8];
#pragma unroll
  for (int k = 0; k < 8; ++k) { pref[k] = s; s += cnt[k]; }
  lsum[t] = s;
  __syncthreads();
  for (int o = 1; o < 256; o <<= 1) {
    int v = (t >= o) ? lsum[t - o] : 0;
    __syncthreads();
    if (t >= o) lsum[t] += v;
    __syncthreads();
  }
  int ex = (t == 0) ? 0 : lsum[t - 1];
#pragma unroll
  for (int k = 0; k < 8; ++k) {
    int r = b * kRowsPerBkt + t * 8 + k;
    if (r < kN) rowptr[r] = ex + pref[k];
  }
  if (t == 255) partials[b] = lsum[255];
}

__global__ void scan2(int* __restrict__ partials) {
  __shared__ int lds[256];
  int t = threadIdx.x;
  lds[t] = (t < kNBKT) ? partials[t] : 0;
  __syncthreads();
  for (int o = 1; o < 256; o <<= 1) {
    int v = (t >= o) ? lds[t - o] : 0;
    __syncthreads();
    if (t >= o) lds[t] += v;
    __syncthreads();
  }
  int ex = (t == 0) ? 0 : lds[t - 1];
  if (t < kNBKT) partials[t] = ex;
}

__global__ void scan3(int* __restrict__ rowptr, const int* __restrict__ partials) {
  int i = blockIdx.x * blockDim.x + threadIdx.x;
  if (i < kN) rowptr[i] += partials[i >> 11];
  else if (i == kN) rowptr[kN] = kNNZ;
}

// Grid = kNBKT*kMC. Place edges to final CSR slots; random writes confined to
// the bucket's ~272 KB window.
__global__ void chunk_place(const int* __restrict__ gpos, const int2* __restrict__ tmp,
                            const int* __restrict__ rowptr, const int* __restrict__ ctab,
                            int2* __restrict__ edges) {
  __shared__ int rank[kRowsPerBkt];
  int b = blockIdx.x / kMC, c = blockIdx.x % kMC;
  int t = threadIdx.x;
  for (int i = t; i < kRowsPerBkt; i += 256) rank[i] = 0;
  __syncthreads();
  int s = b * kCap + c * kCE;
  int e = b * kCap + gpos[b];
  if (s + kCE < e) e = s + kCE;
  const int* coff = ctab + (size_t)blockIdx.x * kRowsPerBkt;
  for (int j = s + t; j < e; j += 256) {
    v2i epk = __builtin_nontemporal_load((const v2i*)(tmp + j));
    int rl = epk.x >> 19;
    int k = atomicAdd(&rank[rl], 1);
    int dst = rowptr[b * kRowsPerBkt + rl] + coff[rl] + k;
    edges[dst] = make_int2(epk.x & 0x7FFFF, epk.y);
  }
}

// --- layer-3 pruning: mark rows actually read by the accumulators.
__global__ void mark_rows(const int* __restrict__ users, const int* __restrict__ items,
                          int* __restrict__ mark) {
  int i = blockIdx.x * blockDim.x + threadIdx.x;
  if (i >= kB) return;
  mark[users[i]] = 1;
  mark[kUsers + items[i]] = 1;
}

__global__ void compact_rows(const int* __restrict__ mark, int* __restrict__ list,
                             int* __restrict__ cnt) {
  int i = blockIdx.x * blockDim.x + threadIdx.x;
  if (i < kN && mark[i]) list[atomicAdd(cnt, 1)] = i;
}

// --- degree-sorted row permutation: waves process equal-degree rows, killing
// the ~1.38x wave-max padding in spmm. 64-bin counting sort off rowptr.
__global__ void deg_hist(const int* __restrict__ rowptr, int* __restrict__ dh) {
  __shared__ int h[64];
  int t = threadIdx.x;
  if (t < 64) h[t] = 0;
  __syncthreads();
  int i = blockIdx.x * 256 + t;
  if (i < kN) {
    int d = min(rowptr[i + 1] - rowptr[i], 63);
    atomicAdd(&h[d], 1);
  }
  __syncthreads();
  if (t < 64 && h[t]) atomicAdd(&dh[t], h[t]);
}

__global__ void deg_scan(int* __restrict__ dh) {   // 1 block, 64 threads (one wave)
  int t = threadIdx.x;
  int v = dh[t];
  int x = v;
  for (int o = 1; o < 64; o <<= 1) {
    int y = __shfl_up(x, o, 64);
    if (t >= o) x += y;
  }
  dh[t] = x - v;   // exclusive
}

__global__ void deg_place(const int* __restrict__ rowptr, int* __restrict__ dh,
                          int* __restrict__ perm) {
  __shared__ int h[64], base[64];
  int t = threadIdx.x;
  if (t < 64) h[t] = 0;
  __syncthreads();
  int i = blockIdx.x * 256 + t;
  int d = 0, lr = 0;
  bool okv = (i < kN);
  if (okv) {
    d = min(rowptr[i + 1] - rowptr[i], 63);
    lr = atomicAdd(&h[d], 1);
  }
  __syncthreads();
  if (t < 64) base[t] = h[t] ? atomicAdd(&dh[t], h[t]) : 0;
  __syncthreads();
  if (okv) perm[base[d] + lr] = i;
}

// Convert concat(uemb, iemb) rows to fp16. One thread per 4 elems.
__global__ void to_half(const float* __restrict__ ue, const float* __restrict__ ie,
                        __half* __restrict__ xh) {
  int t = blockIdx.x * blockDim.x + threadIdx.x;
  if (t >= kN * kD / 4) return;
  int row = t >> 4;
  int g = t & 15;
  const float* src = (row < kUsers) ? (ue + (size_t)row * kD)
                                    : (ie + (size_t)(row - kUsers) * kD);
  v4f v = __builtin_nontemporal_load((const v4f*)src + g);
  __half2 h01 = __float22half2_rn(make_float2(v.x, v.y));
  __half2 h23 = __float22half2_rn(make_float2(v.z, v.w));
  ((int2*)xh)[t] = make_int2(*(int*)&h01, *(int*)&h23);
}

// Reduction-free spmm: one 8-lane group per row (8 rows/wave). Lane l owns
// dims [8l, 8l+8). Unroll-4 with explicit edge-quad prefetch: 4 gathers +
// next-iter edge loads in flight per wave before the first s_waitcnt, ~2x the
// memory-level parallelism of the old unroll-2 (latency-bound regime).
// Rows come from a degree-sorted perm so wave-max degree ~= each row's degree.
template <bool SUBSET>
__global__ __launch_bounds__(256, 8) void spmm(
    const int* __restrict__ rowptr, const int2* __restrict__ edges,
    const __half* __restrict__ x, __half* __restrict__ yh,
    const int* __restrict__ perm, const int* __restrict__ cnt) {
  int t = threadIdx.x;
  int l = t & 7;                               // dim octet
  int wid = (blockIdx.x * 256 + t) >> 6;       // global wave id
  int g = (t >> 3) & 7;                        // group (row) within wave
  int p = wid * 8 + g;
  int r = -1;
  if (SUBSET) {
    int n = *cnt;
    if (p < n) r = perm[p];
  } else {
    if (p < kN) r = perm[p];
  }
  int s = 0, e = 0;
  if (r >= 0) { s = rowptr[r]; e = rowptr[r + 1]; }
  int mx = e - s;
#pragma unroll
  for (int m = 8; m <= 32; m <<= 1) mx = max(mx, __shfl_xor(mx, m, 64));
  float acc[8];
#pragma unroll
  for (int k = 0; k < 8; ++k) acc[k] = 0.f;
  int last = max(e - 1, 0);
  int j = s;
  int2 E0 = edges[min(j, last)];
  int2 E1 = edges[min(j + 1, last)];
  int2 E2 = edges[min(j + 2, last)];
  int2 E3 = edges[min(j + 3, last)];
  for (int it = 0; it < mx; it += 4) {
    float v0 = (j     < e) ? __int_as_float(E0.y) : 0.f;
    float v1 = (j + 1 < e) ? __int_as_float(E1.y) : 0.f;
    float v2 = (j + 2 < e) ? __int_as_float(E2.y) : 0.f;
    float v3 = (j + 3 < e) ? __int_as_float(E3.y) : 0.f;
    v4i h0 = ((const v4i*)(x + (size_t)E0.x * kD))[l];
    v4i h1 = ((const v4i*)(x + (size_t)E1.x * kD))[l];
    v4i h2 = ((const v4i*)(x + (size_t)E2.x * kD))[l];
    v4i h3 = ((const v4i*)(x + (size_t)E3.x * kD))[l];
    j += 4;
    E0 = edges[min(j, last)];                  // prefetch next quad (clamped)
    E1 = edges[min(j + 1, last)];
    E2 = edges[min(j + 2, last)];
    E3 = edges[min(j + 3, last)];
    const __half2* p0 = (const __half2*)&h0;
    const __half2* p1 = (const __half2*)&h1;
    const __half2* p2 = (const __half2*)&h2;
    const __half2* p3 = (const __half2*)&h3;
#pragma unroll
    for (int k = 0; k < 4; ++k) {
      acc[2 * k]     = fmaf(v0, __half2float(__low2half(p0[k])),  acc[2 * k]);
      acc[2 * k + 1] = fmaf(v0, __half2float(__high2half(p0[k])), acc[2 * k + 1]);
    }
#pragma unroll
    for (int k = 0; k < 4; ++k) {
      acc[2 * k]     = fmaf(v1, __half2float(__low2half(p1[k])),  acc[2 * k]);
      acc[2 * k + 1] = fmaf(v1, __half2float(__high2half(p1[k])), acc[2 * k + 1]);
    }
#pragma unroll
    for (int k = 0; k < 4; ++k) {
      acc[2 * k]     = fmaf(v2, __half2float(__low2half(p2[k])),  acc[2 * k]);
      acc[2 * k + 1] = fmaf(v2, __half2float(__high2half(p2[k])), acc[2 * k + 1]);
    }
#pragma unroll
    for (int k = 0; k < 4; ++k) {
      acc[2 * k]     = fmaf(v3, __half2float(__low2half(p3[k])),  acc[2 * k]);
      acc[2 * k + 1] = fmaf(v3, __half2float(__high2half(p3[k])), acc[2 * k + 1]);
    }
  }
  if (r >= 0) {
    v4i pk;
    __half2* ph = (__half2*)&pk;
#pragma unroll
    for (int k = 0; k < 4; ++k)
      ph[k] = __float22half2_rn(make_float2(acc[2 * k], acc[2 * k + 1]));
    if (SUBSET)
      *((v4i*)yh + (size_t)r * 8 + l) = pk;    // small, read immediately after
    else
      __builtin_nontemporal_store(pk, (v4i*)yh + (size_t)r * 8 + l);
  }
}

// acc = emb_gather + layer1 (fuses old acc_init + acc_add; same fp32 add order)
__global__ void acc_add_init(const int* __restrict__ users, const int* __restrict__ items,
                             const float* __restrict__ uemb, const float* __restrict__ iemb,
                             const __half* __restrict__ xh, float* __restrict__ uacc,
                             float* __restrict__ iacc) {
  int tid = blockIdx.x * blockDim.x + threadIdx.x;
  if (tid >= kB * kD) return;
  int b = tid >> 6, d = tid & 63;
  int u = users[b], iw = items[b];
  uacc[tid] = uemb[(size_t)u * kD + d] + __half2float(xh[(size_t)u * kD + d]);
  iacc[tid] = iemb[(size_t)iw * kD + d] + __half2float(xh[(size_t)(kUsers + iw) * kD + d]);
}

__global__ void acc_add(const int* __restrict__ users, const int* __restrict__ items,
                        const __half* __restrict__ xh, float* __restrict__ uacc,
                        float* __restrict__ iacc) {
  int tid = blockIdx.x * blockDim.x + threadIdx.x;
  if (tid >= kB * kD) return;
  int b = tid >> 6, d = tid & 63;
  uacc[tid] += __half2float(xh[(size_t)users[b] * kD + d]);
  iacc[tid] += __half2float(xh[(size_t)(kUsers + items[b]) * kD + d]);
}

// layer-3 accumulate + dot + scale, fused (no uacc/iacc write-back)
__global__ void acc_add_fin(const int* __restrict__ users, const int* __restrict__ items,
                            const __half* __restrict__ xh, const float* __restrict__ uacc,
                            const float* __restrict__ iacc, float* __restrict__ out) {
  int tid = blockIdx.x * blockDim.x + threadIdx.x;
  if (tid >= kB * kD) return;
  int b = tid >> 6, d = tid & 63;
  float u = uacc[tid] + __half2float(xh[(size_t)users[b] * kD + d]);
  float v = iacc[tid] + __half2float(xh[(size_t)(kUsers + items[b]) * kD + d]);
  float p = u * v;
  for (int o = 32; o > 0; o >>= 1) p += __shfl_down(p, o, 64);
  if (d == 0) out[b] = p * 0.0625f;
}

}  // namespace

extern "C" void kernel_launch(void* const* d_in, const int* in_sizes, int n_in,
                              void* d_out, int out_size, void* d_ws, size_t ws_size,
                              hipStream_t stream) {
  const int*   users = (const int*)d_in[0];
  const int*   items = (const int*)d_in[1];
  const int*   erow  = (const int*)d_in[2];
  const int*   ecol  = (const int*)d_in[3];
  const float* evals = (const float*)d_in[4];
  const float* uemb  = (const float*)d_in[5];
  const float* iemb  = (const float*)d_in[6];
  float* out = (float*)d_out;

  char* ws = (char*)d_ws;
  size_t off = 0;
  auto take = [&](size_t bytes) -> char* {
    char* p = ws + off;
    off = (off + bytes + 255) & ~(size_t)255;
    return p;
  };
  int*    rowptr   = (int*)take((size_t)(kN + 1) * 4);
  int*    gpos     = (int*)take((kNBKT + 1) * 4);
  int*    partials = (int*)take(256 * 4);
  int*    mark     = (int*)take((size_t)kN * 4);
  int*    list     = (int*)take((size_t)kMaxSub * 4);
  int*    scnt     = (int*)take(256);
  int2*   edges    = (int2*)take((size_t)kNNZ * 8);
  int2*   tmp      = (int2*)take((size_t)kNBKT * kCap * 8);  // 48.2 MB
  __half* xh0      = (__half*)take((size_t)kN * kD * 2);     // fp16 ping
  __half* xh1      = (__half*)take((size_t)kN * kD * 2);     // fp16 pong
  float*  uacc     = (float*)take((size_t)kB * kD * 4);
  float*  iacc     = (float*)take((size_t)kB * kD * 4);
  int*    ctab     = (int*)xh0;   // 6.0 MB, dead before to_half writes xh0
  int*    perm     = mark;        // mark dead after compact_rows
  int*    dh       = partials;    // partials dead after scan3
  (void)ws_size; (void)in_sizes; (void)n_in; (void)out_size;

  const int nScatBlocks = (kNNZ + kSEPB - 1) / kSEPB;  // 1221
  const int nSpmmBlocks = (kN + 31) / 32;              // 8 rows/wave, 4 waves/block
  const int nSubBlocks  = (kMaxSub + 31) / 32;         // 1024
  const int nRowBlocks  = (kN + 255) / 256;            // 1172

  // --- CSR build: fixed-capacity bucket sort, then parallel counting sort ---
  zero_i32<<<1, 256, 0, stream>>>(gpos, kNBKT + 1);
  zero_i32<<<nRowBlocks, 256, 0, stream>>>(mark, kN);
  zero_i32<<<1, 64, 0, stream>>>(scnt, 1);
  bucket_scatter<<<nScatBlocks, 256, 0, stream>>>(erow, ecol, evals, gpos, tmp);
  chunk_hist<<<kNBKT * kMC, 256, 0, stream>>>(gpos, tmp, ctab);
  scanA<<<kNBKT, 256, 0, stream>>>(ctab, rowptr, partials);
  scan2<<<1, 256, 0, stream>>>(partials);
  scan3<<<(kN + 1 + 255) / 256, 256, 0, stream>>>(rowptr, partials);
  chunk_place<<<kNBKT * kMC, 256, 0, stream>>>(gpos, tmp, rowptr, ctab, edges);

  // --- layer-3 row subset (rows read by the accumulators) ---
  mark_rows<<<(kB + 255) / 256, 256, 0, stream>>>(users, items, mark);
  compact_rows<<<nRowBlocks, 256, 0, stream>>>(mark, list, scnt);

  // --- degree-sorted row permutation (perm aliases mark, dh aliases partials)
  zero_i32<<<1, 64, 0, stream>>>(dh, 64);
  deg_hist<<<nRowBlocks, 256, 0, stream>>>(rowptr, dh);
  deg_scan<<<1, 64, 0, stream>>>(dh);
  deg_place<<<nRowBlocks, 256, 0, stream>>>(rowptr, dh, perm);

  // --- fp16 copy of concat embeddings (after chunk_place: ctab aliases xh0) ---
  to_half<<<(kN * kD / 4 + 255) / 256, 256, 0, stream>>>(uemb, iemb, xh0);

  // --- 3 propagation layers; fp16 ping-pong; layer 3 pruned to subset ---
  spmm<false><<<nSpmmBlocks, 256, 0, stream>>>(rowptr, edges, xh0, xh1, perm, nullptr);
  acc_add_init<<<(kB * kD) / 256, 256, 0, stream>>>(users, items, uemb, iemb, xh1, uacc, iacc);
  spmm<false><<<nSpmmBlocks, 256, 0, stream>>>(rowptr, edges, xh1, xh0, perm, nullptr);
  acc_add<<<(kB * kD) / 256, 256, 0, stream>>>(users, items, xh0, uacc, iacc);
  spmm<true ><<<nSubBlocks, 256, 0, stream>>>(rowptr, edges, xh0, xh1, list, scnt);
  acc_add_fin<<<(kB * kD) / 256, 256, 0, stream>>>(users, items, xh1, uacc, iacc, out);
}

// Round 2
// 635.248 us; speedup vs baseline: 1.1578x; 1.1578x over previous
//
#include <hip/hip_runtime.h>
#include <hip/hip_fp16.h>

namespace {

constexpr int kUsers = 100000;
constexpr int kItems = 200000;
constexpr int kN     = kUsers + kItems;   // 300000
constexpr int kD     = 64;
constexpr int kNNZ   = 5000000;
constexpr int kB     = 16384;
constexpr int kRowsPerBkt = 2048;                       // rows per coarse bucket
constexpr int kNBKT  = (kN + kRowsPerBkt - 1) / kRowsPerBkt;  // 147
constexpr int kSEPB  = 4096;                            // edges per bucket_scatter block
constexpr int kCE    = 8192;                            // edges per finalize chunk
constexpr int kMC    = 5;                               // chunks per bucket
constexpr int kCap   = kMC * kCE;                       // 40960 slots/bucket (mean 34133, sd 185)
constexpr int kMaxSub = 2 * kB;                         // upper bound on marked rows

typedef int   v4i __attribute__((ext_vector_type(4)));
typedef float v4f __attribute__((ext_vector_type(4)));

__global__ void zero_i32(int* __restrict__ p, int n) {
  int i = blockIdx.x * blockDim.x + threadIdx.x;
  if (i < n) p[i] = 0;
}

// Counting-sort partition of 4096 edges into 147 coarse buckets; per-wave LDS
// histograms (4x147) cut same-address atomic serialization 4x. LDS staging so
// tmp writes go out in coalesced bucket-run bursts.
// NOTE on cache policy (round-1 post-mortem): tmp is written once and READ
// TWICE (chunk_hist + chunk_place) -> plain stores so it stays in L2/L3.
// Only the input streams (row/col/val, read exactly once ever) are nt.
__global__ void bucket_scatter(const int* __restrict__ row, const int* __restrict__ col,
                               const float* __restrict__ val, int* __restrict__ gpos,
                               int2* __restrict__ tmp) {
  __shared__ int hcnt[4][kNBKT];   // per-wave counts -> wave-exclusive offsets
  __shared__ int lofs[kNBKT];
  __shared__ int hbase[kNBKT];
  __shared__ int lds[256];
  __shared__ int2 se[kSEPB];
  __shared__ unsigned short sb[kSEPB];
  int t = threadIdx.x;
  int wv = t >> 6;
  long base = (long)blockIdx.x * kSEPB;
  int valid = (int)min((long)kSEPB, (long)kNNZ - base);
  for (int i = t; i < kNBKT; i += 256) {
    hcnt[0][i] = 0; hcnt[1][i] = 0; hcnt[2][i] = 0; hcnt[3][i] = 0;
  }
  __syncthreads();
  int pk[16], bk[16], rk[16];
  float v[16];
  bool ok[16];
#pragma unroll
  for (int j = 0; j < 16; ++j) {
    long i = base + j * 256 + t;
    ok[j] = (i < kNNZ);
    if (ok[j]) {
      int r = __builtin_nontemporal_load(row + i);
      bk[j] = r >> 11;
      pk[j] = ((r & 2047) << 19) | __builtin_nontemporal_load(col + i);
      v[j] = __builtin_nontemporal_load(val + i);
      rk[j] = atomicAdd(&hcnt[wv][bk[j]], 1);
    }
  }
  __syncthreads();
  // per-bucket: wave-exclusive offsets + total; then block scan of totals
  int own = 0;
  if (t < kNBKT) {
    int c0 = hcnt[0][t], c1 = hcnt[1][t], c2 = hcnt[2][t], c3 = hcnt[3][t];
    hcnt[0][t] = 0; hcnt[1][t] = c0; hcnt[2][t] = c0 + c1; hcnt[3][t] = c0 + c1 + c2;
    own = c0 + c1 + c2 + c3;
  }
  lds[t] = own;
  __syncthreads();
  for (int o = 1; o < 256; o <<= 1) {
    int x = (t >= o) ? lds[t - o] : 0;
    __syncthreads();
    if (t >= o) lds[t] += x;
    __syncthreads();
  }
  if (t < kNBKT) {
    lofs[t] = lds[t] - own;
    hbase[t] = t * kCap + atomicAdd(&gpos[t], own);
  }
  __syncthreads();
  // place into LDS in bucket-sorted order
#pragma unroll
  for (int j = 0; j < 16; ++j) {
    if (ok[j]) {
      int pos = lofs[bk[j]] + hcnt[wv][bk[j]] + rk[j];
      se[pos] = make_int2(pk[j], __float_as_int(v[j]));
      sb[pos] = (unsigned short)bk[j];
    }
  }
  __syncthreads();
  // drain LDS sequentially -> coalesced global runs (plain stores: L2-resident)
#pragma unroll
  for (int j = 0; j < 16; ++j) {
    int pos = t + j * 256;
    if (pos < valid) {
      int b = sb[pos];
      tmp[hbase[b] + (pos - lofs[b])] = se[pos];
    }
  }
}

// Grid = kNBKT*kMC. Per-(bucket,chunk) 2048-row LDS histogram -> ctab.
__global__ void chunk_hist(const int* __restrict__ gpos, const int2* __restrict__ tmp,
                           int* __restrict__ ctab) {
  __shared__ int h[kRowsPerBkt];
  int b = blockIdx.x / kMC, c = blockIdx.x % kMC;
  int t = threadIdx.x;
  for (int i = t; i < kRowsPerBkt; i += 256) h[i] = 0;
  __syncthreads();
  int s = b * kCap + c * kCE;
  int e = b * kCap + gpos[b];
  if (s + kCE < e) e = s + kCE;
  for (int j = s + t; j < e; j += 256) atomicAdd(&h[tmp[j].x >> 19], 1);
  __syncthreads();
  int* dst = ctab + (size_t)blockIdx.x * kRowsPerBkt;
  for (int i = t; i < kRowsPerBkt; i += 256) dst[i] = h[i];
}

// Per-row totals over chunks (ctab -> chunk-exclusive prefixes), block-scan of
// 2048 row totals -> bucket-local rowptr + per-bucket partial.
__global__ void scanA(int* __restrict__ ctab, int* __restrict__ rowptr,
                      int* __restrict__ partials) {
  __shared__ int lsum[256];
  int b = blockIdx.x, t = threadIdx.x;
  int cnt[8];
#pragma unroll
  for (int k = 0; k < 8; ++k) cnt[k] = 0;
  for (int c = 0; c < kMC; ++c) {
    int* p = ctab + (size_t)(b * kMC + c) * kRowsPerBkt;
#pragma unroll
    for (int k = 0; k < 8; ++k) {
      int idx = t * 8 + k;
      int v = p[idx];
      p[idx] = cnt[k];
      cnt[k] += v;
    }
  }
  int s = 0, pref[8];
#pragma unroll
  for (int k = 0; k < 8; ++k) { pref[k] = s; s += cnt[k]; }
  lsum[t] = s;
  __syncthreads();
  for (int o = 1; o < 256; o <<= 1) {
    int v = (t >= o) ? lsum[t - o] : 0;
    __syncthreads();
    if (t >= o) lsum[t] += v;
    __syncthreads();
  }
  int ex = (t == 0) ? 0 : lsum[t - 1];
#pragma unroll
  for (int k = 0; k < 8; ++k) {
    int r = b * kRowsPerBkt + t * 8 + k;
    if (r < kN) rowptr[r] = ex + pref[k];
  }
  if (t == 255) partials[b] = lsum[255];
}

__global__ void scan2(int* __restrict__ partials) {
  __shared__ int lds[256];
  int t = threadIdx.x;
  lds[t] = (t < kNBKT) ? partials[t] : 0;
  __syncthreads();
  for (int o = 1; o < 256; o <<= 1) {
    int v = (t >= o) ? lds[t - o] : 0;
    __syncthreads();
    if (t >= o) lds[t] += v;
    __syncthreads();
  }
  int ex = (t == 0) ? 0 : lds[t - 1];
  if (t < kNBKT) partials[t] = ex;
}

__global__ void scan3(int* __restrict__ rowptr, const int* __restrict__ partials) {
  int i = blockIdx.x * blockDim.x + threadIdx.x;
  if (i < kN) rowptr[i] += partials[i >> 11];
  else if (i == kN) rowptr[kN] = kNNZ;
}

// Grid = kNBKT*kMC. Place edges to final CSR slots; random writes confined to
// the bucket's ~272 KB window. Plain tmp loads: served from L2/L3.
__global__ void chunk_place(const int* __restrict__ gpos, const int2* __restrict__ tmp,
                            const int* __restrict__ rowptr, const int* __restrict__ ctab,
                            int2* __restrict__ edges) {
  __shared__ int rank[kRowsPerBkt];
  int b = blockIdx.x / kMC, c = blockIdx.x % kMC;
  int t = threadIdx.x;
  for (int i = t; i < kRowsPerBkt; i += 256) rank[i] = 0;
  __syncthreads();
  int s = b * kCap + c * kCE;
  int e = b * kCap + gpos[b];
  if (s + kCE < e) e = s + kCE;
  const int* coff = ctab + (size_t)blockIdx.x * kRowsPerBkt;
  for (int j = s + t; j < e; j += 256) {
    int2 epk = tmp[j];
    int rl = epk.x >> 19;
    int k = atomicAdd(&rank[rl], 1);
    int dst = rowptr[b * kRowsPerBkt + rl] + coff[rl] + k;
    edges[dst] = make_int2(epk.x & 0x7FFFF, epk.y);
  }
}

// --- layer-3 pruning: mark rows actually read by the accumulators.
__global__ void mark_rows(const int* __restrict__ users, const int* __restrict__ items,
                          int* __restrict__ mark) {
  int i = blockIdx.x * blockDim.x + threadIdx.x;
  if (i >= kB) return;
  mark[users[i]] = 1;
  mark[kUsers + items[i]] = 1;
}

__global__ void compact_rows(const int* __restrict__ mark, int* __restrict__ list,
                             int* __restrict__ cnt) {
  int i = blockIdx.x * blockDim.x + threadIdx.x;
  if (i < kN && mark[i]) list[atomicAdd(cnt, 1)] = i;
}

// --- degree-sorted row permutation: waves process equal-degree rows, killing
// the ~1.38x wave-max padding in spmm. 64-bin counting sort off rowptr.
__global__ void deg_hist(const int* __restrict__ rowptr, int* __restrict__ dh) {
  __shared__ int h[64];
  int t = threadIdx.x;
  if (t < 64) h[t] = 0;
  __syncthreads();
  int i = blockIdx.x * 256 + t;
  if (i < kN) {
    int d = min(rowptr[i + 1] - rowptr[i], 63);
    atomicAdd(&h[d], 1);
  }
  __syncthreads();
  if (t < 64 && h[t]) atomicAdd(&dh[t], h[t]);
}

__global__ void deg_scan(int* __restrict__ dh) {   // 1 block, 64 threads (one wave)
  int t = threadIdx.x;
  int v = dh[t];
  int x = v;
  for (int o = 1; o < 64; o <<= 1) {
    int y = __shfl_up(x, o, 64);
    if (t >= o) x += y;
  }
  dh[t] = x - v;   // exclusive
}

__global__ void deg_place(const int* __restrict__ rowptr, int* __restrict__ dh,
                          int* __restrict__ perm) {
  __shared__ int h[64], base[64];
  int t = threadIdx.x;
  if (t < 64) h[t] = 0;
  __syncthreads();
  int i = blockIdx.x * 256 + t;
  int d = 0, lr = 0;
  bool okv = (i < kN);
  if (okv) {
    d = min(rowptr[i + 1] - rowptr[i], 63);
    lr = atomicAdd(&h[d], 1);
  }
  __syncthreads();
  if (t < 64) base[t] = h[t] ? atomicAdd(&dh[t], h[t]) : 0;
  __syncthreads();
  if (okv) perm[base[d] + lr] = i;
}

// Convert concat(uemb, iemb) rows to fp16. One thread per 4 elems.
// nt load ok: fp32 embeddings are never re-read except acc_add_init's tiny
// gather; keeping 77 MB of fp32 out of L3 leaves room for tmp/edges/xh.
__global__ void to_half(const float* __restrict__ ue, const float* __restrict__ ie,
                        __half* __restrict__ xh) {
  int t = blockIdx.x * blockDim.x + threadIdx.x;
  if (t >= kN * kD / 4) return;
  int row = t >> 4;
  int g = t & 15;
  const float* src = (row < kUsers) ? (ue + (size_t)row * kD)
                                    : (ie + (size_t)(row - kUsers) * kD);
  v4f v = __builtin_nontemporal_load((const v4f*)src + g);
  __half2 h01 = __float22half2_rn(make_float2(v.x, v.y));
  __half2 h23 = __float22half2_rn(make_float2(v.z, v.w));
  ((int2*)xh)[t] = make_int2(*(int*)&h01, *(int*)&h23);
}

// Reduction-free spmm: one 8-lane group per row (8 rows/wave). Lane l owns
// dims [8l, 8l+8). Unroll-4 with explicit edge-quad prefetch: 4 gathers +
// next-iter edge loads in flight per wave before the first s_waitcnt, ~2x the
// memory-level parallelism of the old unroll-2 (latency-bound regime).
// Rows come from a degree-sorted perm so wave-max degree ~= each row's degree.
// Output store is PLAIN: the next layer gathers from it (round-1 lesson).
template <bool SUBSET>
__global__ __launch_bounds__(256, 8) void spmm(
    const int* __restrict__ rowptr, const int2* __restrict__ edges,
    const __half* __restrict__ x, __half* __restrict__ yh,
    const int* __restrict__ perm, const int* __restrict__ cnt) {
  int t = threadIdx.x;
  int l = t & 7;                               // dim octet
  int wid = (blockIdx.x * 256 + t) >> 6;       // global wave id
  int g = (t >> 3) & 7;                        // group (row) within wave
  int p = wid * 8 + g;
  int r = -1;
  if (SUBSET) {
    int n = *cnt;
    if (p < n) r = perm[p];
  } else {
    if (p < kN) r = perm[p];
  }
  int s = 0, e = 0;
  if (r >= 0) { s = rowptr[r]; e = rowptr[r + 1]; }
  int mx = e - s;
#pragma unroll
  for (int m = 8; m <= 32; m <<= 1) mx = max(mx, __shfl_xor(mx, m, 64));
  float acc[8];
#pragma unroll
  for (int k = 0; k < 8; ++k) acc[k] = 0.f;
  int last = max(e - 1, 0);
  int j = s;
  int2 E0 = edges[min(j, last)];
  int2 E1 = edges[min(j + 1, last)];
  int2 E2 = edges[min(j + 2, last)];
  int2 E3 = edges[min(j + 3, last)];
  for (int it = 0; it < mx; it += 4) {
    float v0 = (j     < e) ? __int_as_float(E0.y) : 0.f;
    float v1 = (j + 1 < e) ? __int_as_float(E1.y) : 0.f;
    float v2 = (j + 2 < e) ? __int_as_float(E2.y) : 0.f;
    float v3 = (j + 3 < e) ? __int_as_float(E3.y) : 0.f;
    v4i h0 = ((const v4i*)(x + (size_t)E0.x * kD))[l];
    v4i h1 = ((const v4i*)(x + (size_t)E1.x * kD))[l];
    v4i h2 = ((const v4i*)(x + (size_t)E2.x * kD))[l];
    v4i h3 = ((const v4i*)(x + (size_t)E3.x * kD))[l];
    j += 4;
    E0 = edges[min(j, last)];                  // prefetch next quad (clamped)
    E1 = edges[min(j + 1, last)];
    E2 = edges[min(j + 2, last)];
    E3 = edges[min(j + 3, last)];
    const __half2* p0 = (const __half2*)&h0;
    const __half2* p1 = (const __half2*)&h1;
    const __half2* p2 = (const __half2*)&h2;
    const __half2* p3 = (const __half2*)&h3;
#pragma unroll
    for (int k = 0; k < 4; ++k) {
      acc[2 * k]     = fmaf(v0, __half2float(__low2half(p0[k])),  acc[2 * k]);
      acc[2 * k + 1] = fmaf(v0, __half2float(__high2half(p0[k])), acc[2 * k + 1]);
    }
#pragma unroll
    for (int k = 0; k < 4; ++k) {
      acc[2 * k]     = fmaf(v1, __half2float(__low2half(p1[k])),  acc[2 * k]);
      acc[2 * k + 1] = fmaf(v1, __half2float(__high2half(p1[k])), acc[2 * k + 1]);
    }
#pragma unroll
    for (int k = 0; k < 4; ++k) {
      acc[2 * k]     = fmaf(v2, __half2float(__low2half(p2[k])),  acc[2 * k]);
      acc[2 * k + 1] = fmaf(v2, __half2float(__high2half(p2[k])), acc[2 * k + 1]);
    }
#pragma unroll
    for (int k = 0; k < 4; ++k) {
      acc[2 * k]     = fmaf(v3, __half2float(__low2half(p3[k])),  acc[2 * k]);
      acc[2 * k + 1] = fmaf(v3, __half2float(__high2half(p3[k])), acc[2 * k + 1]);
    }
  }
  if (r >= 0) {
    v4i pk;
    __half2* ph = (__half2*)&pk;
#pragma unroll
    for (int k = 0; k < 4; ++k)
      ph[k] = __float22half2_rn(make_float2(acc[2 * k], acc[2 * k + 1]));
    *((v4i*)yh + (size_t)r * 8 + l) = pk;
  }
}

// acc = emb_gather + layer1 (fuses old acc_init + acc_add; same fp32 add order)
__global__ void acc_add_init(const int* __restrict__ users, const int* __restrict__ items,
                             const float* __restrict__ uemb, const float* __restrict__ iemb,
                             const __half* __restrict__ xh, float* __restrict__ uacc,
                             float* __restrict__ iacc) {
  int tid = blockIdx.x * blockDim.x + threadIdx.x;
  if (tid >= kB * kD) return;
  int b = tid >> 6, d = tid & 63;
  int u = users[b], iw = items[b];
  uacc[tid] = uemb[(size_t)u * kD + d] + __half2float(xh[(size_t)u * kD + d]);
  iacc[tid] = iemb[(size_t)iw * kD + d] + __half2float(xh[(size_t)(kUsers + iw) * kD + d]);
}

__global__ void acc_add(const int* __restrict__ users, const int* __restrict__ items,
                        const __half* __restrict__ xh, float* __restrict__ uacc,
                        float* __restrict__ iacc) {
  int tid = blockIdx.x * blockDim.x + threadIdx.x;
  if (tid >= kB * kD) return;
  int b = tid >> 6, d = tid & 63;
  uacc[tid] += __half2float(xh[(size_t)users[b] * kD + d]);
  iacc[tid] += __half2float(xh[(size_t)(kUsers + items[b]) * kD + d]);
}

// layer-3 accumulate + dot + scale, fused (no uacc/iacc write-back)
__global__ void acc_add_fin(const int* __restrict__ users, const int* __restrict__ items,
                            const __half* __restrict__ xh, const float* __restrict__ uacc,
                            const float* __restrict__ iacc, float* __restrict__ out) {
  int tid = blockIdx.x * blockDim.x + threadIdx.x;
  if (tid >= kB * kD) return;
  int b = tid >> 6, d = tid & 63;
  float u = uacc[tid] + __half2float(xh[(size_t)users[b] * kD + d]);
  float v = iacc[tid] + __half2float(xh[(size_t)(kUsers + items[b]) * kD + d]);
  float p = u * v;
  for (int o = 32; o > 0; o >>= 1) p += __shfl_down(p, o, 64);
  if (d == 0) out[b] = p * 0.0625f;
}

}  // namespace

extern "C" void kernel_launch(void* const* d_in, const int* in_sizes, int n_in,
                              void* d_out, int out_size, void* d_ws, size_t ws_size,
                              hipStream_t stream) {
  const int*   users = (const int*)d_in[0];
  const int*   items = (const int*)d_in[1];
  const int*   erow  = (const int*)d_in[2];
  const int*   ecol  = (const int*)d_in[3];
  const float* evals = (const float*)d_in[4];
  const float* uemb  = (const float*)d_in[5];
  const float* iemb  = (const float*)d_in[6];
  float* out = (float*)d_out;

  char* ws = (char*)d_ws;
  size_t off = 0;
  auto take = [&](size_t bytes) -> char* {
    char* p = ws + off;
    off = (off + bytes + 255) & ~(size_t)255;
    return p;
  };
  int*    rowptr   = (int*)take((size_t)(kN + 1) * 4);
  int*    gpos     = (int*)take((kNBKT + 1) * 4);
  int*    partials = (int*)take(256 * 4);
  int*    mark     = (int*)take((size_t)kN * 4);
  int*    list     = (int*)take((size_t)kMaxSub * 4);
  int*    scnt     = (int*)take(256);
  int2*   edges    = (int2*)take((size_t)kNNZ * 8);
  int2*   tmp      = (int2*)take((size_t)kNBKT * kCap * 8);  // 48.2 MB
  __half* xh0      = (__half*)take((size_t)kN * kD * 2);     // fp16 ping
  __half* xh1      = (__half*)take((size_t)kN * kD * 2);     // fp16 pong
  float*  uacc     = (float*)take((size_t)kB * kD * 4);
  float*  iacc     = (float*)take((size_t)kB * kD * 4);
  int*    ctab     = (int*)xh0;   // 6.0 MB, dead before to_half writes xh0
  int*    perm     = mark;        // mark dead after compact_rows
  int*    dh       = partials;    // partials dead after scan3
  (void)ws_size; (void)in_sizes; (void)n_in; (void)out_size;

  const int nScatBlocks = (kNNZ + kSEPB - 1) / kSEPB;  // 1221
  const int nSpmmBlocks = (kN + 31) / 32;              // 8 rows/wave, 4 waves/block
  const int nSubBlocks  = (kMaxSub + 31) / 32;         // 1024
  const int nRowBlocks  = (kN + 255) / 256;            // 1172

  // --- CSR build: fixed-capacity bucket sort, then parallel counting sort ---
  zero_i32<<<1, 256, 0, stream>>>(gpos, kNBKT + 1);
  zero_i32<<<nRowBlocks, 256, 0, stream>>>(mark, kN);
  zero_i32<<<1, 64, 0, stream>>>(scnt, 1);
  bucket_scatter<<<nScatBlocks, 256, 0, stream>>>(erow, ecol, evals, gpos, tmp);
  chunk_hist<<<kNBKT * kMC, 256, 0, stream>>>(gpos, tmp, ctab);
  scanA<<<kNBKT, 256, 0, stream>>>(ctab, rowptr, partials);
  scan2<<<1, 256, 0, stream>>>(partials);
  scan3<<<(kN + 1 + 255) / 256, 256, 0, stream>>>(rowptr, partials);
  chunk_place<<<kNBKT * kMC, 256, 0, stream>>>(gpos, tmp, rowptr, ctab, edges);

  // --- layer-3 row subset (rows read by the accumulators) ---
  mark_rows<<<(kB + 255) / 256, 256, 0, stream>>>(users, items, mark);
  compact_rows<<<nRowBlocks, 256, 0, stream>>>(mark, list, scnt);

  // --- degree-sorted row permutation (perm aliases mark, dh aliases partials)
  zero_i32<<<1, 64, 0, stream>>>(dh, 64);
  deg_hist<<<nRowBlocks, 256, 0, stream>>>(rowptr, dh);
  deg_scan<<<1, 64, 0, stream>>>(dh);
  deg_place<<<nRowBlocks, 256, 0, stream>>>(rowptr, dh, perm);

  // --- fp16 copy of concat embeddings (after chunk_place: ctab aliases xh0) ---
  to_half<<<(kN * kD / 4 + 255) / 256, 256, 0, stream>>>(uemb, iemb, xh0);

  // --- 3 propagation layers; fp16 ping-pong; layer 3 pruned to subset ---
  spmm<false><<<nSpmmBlocks, 256, 0, stream>>>(rowptr, edges, xh0, xh1, perm, nullptr);
  acc_add_init<<<(kB * kD) / 256, 256, 0, stream>>>(users, items, uemb, iemb, xh1, uacc, iacc);
  spmm<false><<<nSpmmBlocks, 256, 0, stream>>>(rowptr, edges, xh1, xh0, perm, nullptr);
  acc_add<<<(kB * kD) / 256, 256, 0, stream>>>(users, items, xh0, uacc, iacc);
  spmm<true ><<<nSubBlocks, 256, 0, stream>>>(rowptr, edges, xh0, xh1, list, scnt);
  acc_add_fin<<<(kB * kD) / 256, 256, 0, stream>>>(users, items, xh1, uacc, iacc, out);
}

// Round 3
// 543.354 us; speedup vs baseline: 1.3536x; 1.1691x over previous
//
#include <hip/hip_runtime.h>
#include <hip/hip_fp16.h>
#include <hip/hip_fp8.h>

namespace {

constexpr int kUsers = 100000;
constexpr int kItems = 200000;
constexpr int kN     = kUsers + kItems;   // 300000
constexpr int kD     = 64;
constexpr int kNNZ   = 5000000;
constexpr int kB     = 16384;
constexpr int kRowsPerBkt = 2048;                       // rows per coarse bucket
constexpr int kNBKT  = (kN + kRowsPerBkt - 1) / kRowsPerBkt;  // 147
constexpr int kSEPB  = 4096;                            // edges per bucket_scatter block
constexpr int kCE    = 8192;                            // edges per finalize chunk
constexpr int kMC    = 5;                               // chunks per bucket
constexpr int kCap   = kMC * kCE;                       // 40960 slots/bucket (mean 34133, sd 185)
constexpr int kMaxSub = 2 * kB;                         // upper bound on marked rows

typedef int   v2i __attribute__((ext_vector_type(2)));
typedef float v4f __attribute__((ext_vector_type(4)));

// --- fp8 e4m3 storage convention: buffers hold 64*true_value ("S=64" scale,
// keeps x-magnitudes in e4m3 normal range). Decode trick: e4m3 byte -> fp16
// bits ((b&0x7f)<<7)|((b&0x80)<<8) gives value/256 EXACTLY (incl subnormals,
// which land on fp16 subnormals with identical alignment). The x256 is folded
// into the edge weight; the /64 app-scale is folded into acc_add (x4 on raw).

__device__ inline void dec4(unsigned int w, float& f0, float& f1, float& f2, float& f3) {
  unsigned int a = ((w & 0x007f007fu) << 7) | ((w & 0x00800080u) << 8);          // bytes 0,2
  unsigned int b = (((w >> 8) & 0x007f007fu) << 7) | (((w >> 8) & 0x00800080u) << 8); // 1,3
  float2 e = __half22float2(*reinterpret_cast<const __half2*>(&a));
  float2 o = __half22float2(*reinterpret_cast<const __half2*>(&b));
  f0 = e.x; f1 = o.x; f2 = e.y; f3 = o.y;   // raw = stored/256
}

__device__ inline float dec1x4(unsigned char b) {  // stored(=64*true) -> true
  unsigned int hb = ((b & 0x7fu) << 7) | ((b & 0x80u) << 8);
  return __half2float(__ushort_as_half((unsigned short)hb)) * 4.0f;  // /256*256/64
}

__device__ inline unsigned char enc(float f) { __hip_fp8_e4m3 q(f); return q.__x; }

__global__ void zero_i32(int* __restrict__ p, int n) {
  int i = blockIdx.x * blockDim.x + threadIdx.x;
  if (i < n) p[i] = 0;
}

// Counting-sort partition of 4096 edges into 147 coarse buckets; per-wave LDS
// histograms (4x147) cut same-address atomic serialization 4x. LDS staging so
// tmp writes go out in coalesced bucket-run bursts. tmp is read twice later ->
// plain stores (L2/L3-resident); only the read-once input streams are nt.
__global__ void bucket_scatter(const int* __restrict__ row, const int* __restrict__ col,
                               const float* __restrict__ val, int* __restrict__ gpos,
                               int2* __restrict__ tmp) {
  __shared__ int hcnt[4][kNBKT];   // per-wave counts -> wave-exclusive offsets
  __shared__ int lofs[kNBKT];
  __shared__ int hbase[kNBKT];
  __shared__ int lds[256];
  __shared__ int2 se[kSEPB];
  __shared__ unsigned short sb[kSEPB];
  int t = threadIdx.x;
  int wv = t >> 6;
  long base = (long)blockIdx.x * kSEPB;
  int valid = (int)min((long)kSEPB, (long)kNNZ - base);
  for (int i = t; i < kNBKT; i += 256) {
    hcnt[0][i] = 0; hcnt[1][i] = 0; hcnt[2][i] = 0; hcnt[3][i] = 0;
  }
  __syncthreads();
  int pk[16], bk[16], rk[16];
  float v[16];
  bool ok[16];
#pragma unroll
  for (int j = 0; j < 16; ++j) {
    long i = base + j * 256 + t;
    ok[j] = (i < kNNZ);
    if (ok[j]) {
      int r = __builtin_nontemporal_load(row + i);
      bk[j] = r >> 11;
      pk[j] = ((r & 2047) << 19) | __builtin_nontemporal_load(col + i);
      v[j] = __builtin_nontemporal_load(val + i);
      rk[j] = atomicAdd(&hcnt[wv][bk[j]], 1);
    }
  }
  __syncthreads();
  int own = 0;
  if (t < kNBKT) {
    int c0 = hcnt[0][t], c1 = hcnt[1][t], c2 = hcnt[2][t], c3 = hcnt[3][t];
    hcnt[0][t] = 0; hcnt[1][t] = c0; hcnt[2][t] = c0 + c1; hcnt[3][t] = c0 + c1 + c2;
    own = c0 + c1 + c2 + c3;
  }
  lds[t] = own;
  __syncthreads();
  for (int o = 1; o < 256; o <<= 1) {
    int x = (t >= o) ? lds[t - o] : 0;
    __syncthreads();
    if (t >= o) lds[t] += x;
    __syncthreads();
  }
  if (t < kNBKT) {
    lofs[t] = lds[t] - own;
    hbase[t] = t * kCap + atomicAdd(&gpos[t], own);
  }
  __syncthreads();
#pragma unroll
  for (int j = 0; j < 16; ++j) {
    if (ok[j]) {
      int pos = lofs[bk[j]] + hcnt[wv][bk[j]] + rk[j];
      se[pos] = make_int2(pk[j], __float_as_int(v[j]));
      sb[pos] = (unsigned short)bk[j];
    }
  }
  __syncthreads();
#pragma unroll
  for (int j = 0; j < 16; ++j) {
    int pos = t + j * 256;
    if (pos < valid) {
      int b = sb[pos];
      tmp[hbase[b] + (pos - lofs[b])] = se[pos];
    }
  }
}

// Grid = kNBKT*kMC. Per-(bucket,chunk) 2048-row LDS histogram -> ctab.
__global__ void chunk_hist(const int* __restrict__ gpos, const int2* __restrict__ tmp,
                           int* __restrict__ ctab) {
  __shared__ int h[kRowsPerBkt];
  int b = blockIdx.x / kMC, c = blockIdx.x % kMC;
  int t = threadIdx.x;
  for (int i = t; i < kRowsPerBkt; i += 256) h[i] = 0;
  __syncthreads();
  int s = b * kCap + c * kCE;
  int e = b * kCap + gpos[b];
  if (s + kCE < e) e = s + kCE;
  for (int j = s + t; j < e; j += 256) atomicAdd(&h[tmp[j].x >> 19], 1);
  __syncthreads();
  int* dst = ctab + (size_t)blockIdx.x * kRowsPerBkt;
  for (int i = t; i < kRowsPerBkt; i += 256) dst[i] = h[i];
}

__global__ void scanA(int* __restrict__ ctab, int* __restrict__ rowptr,
                      int* __restrict__ partials) {
  __shared__ int lsum[256];
  int b = blockIdx.x, t = threadIdx.x;
  int cnt[8];
#pragma unroll
  for (int k = 0; k < 8; ++k) cnt[k] = 0;
  for (int c = 0; c < kMC; ++c) {
    int* p = ctab + (size_t)(b * kMC + c) * kRowsPerBkt;
#pragma unroll
    for (int k = 0; k < 8; ++k) {
      int idx = t * 8 + k;
      int v = p[idx];
      p[idx] = cnt[k];
      cnt[k] += v;
    }
  }
  int s = 0, pref[8];
#pragma unroll
  for (int k = 0; k < 8; ++k) { pref[k] = s; s += cnt[k]; }
  lsum[t] = s;
  __syncthreads();
  for (int o = 1; o < 256; o <<= 1) {
    int v = (t >= o) ? lsum[t - o] : 0;
    __syncthreads();
    if (t >= o) lsum[t] += v;
    __syncthreads();
  }
  int ex = (t == 0) ? 0 : lsum[t - 1];
#pragma unroll
  for (int k = 0; k < 8; ++k) {
    int r = b * kRowsPerBkt + t * 8 + k;
    if (r < kN) rowptr[r] = ex + pref[k];
  }
  if (t == 255) partials[b] = lsum[255];
}

__global__ void scan2(int* __restrict__ partials) {
  __shared__ int lds[256];
  int t = threadIdx.x;
  lds[t] = (t < kNBKT) ? partials[t] : 0;
  __syncthreads();
  for (int o = 1; o < 256; o <<= 1) {
    int v = (t >= o) ? lds[t - o] : 0;
    __syncthreads();
    if (t >= o) lds[t] += v;
    __syncthreads();
  }
  int ex = (t == 0) ? 0 : lds[t - 1];
  if (t < kNBKT) partials[t] = ex;
}

__global__ void scan3(int* __restrict__ rowptr, const int* __restrict__ partials) {
  int i = blockIdx.x * blockDim.x + threadIdx.x;
  if (i < kN) rowptr[i] += partials[i >> 11];
  else if (i == kN) rowptr[kN] = kNNZ;
}

// Grid = kNBKT*kMC. Place edges to final CSR slots; random writes confined to
// the bucket's ~272 KB window.
__global__ void chunk_place(const int* __restrict__ gpos, const int2* __restrict__ tmp,
                            const int* __restrict__ rowptr, const int* __restrict__ ctab,
                            int2* __restrict__ edges) {
  __shared__ int rank[kRowsPerBkt];
  int b = blockIdx.x / kMC, c = blockIdx.x % kMC;
  int t = threadIdx.x;
  for (int i = t; i < kRowsPerBkt; i += 256) rank[i] = 0;
  __syncthreads();
  int s = b * kCap + c * kCE;
  int e = b * kCap + gpos[b];
  if (s + kCE < e) e = s + kCE;
  const int* coff = ctab + (size_t)blockIdx.x * kRowsPerBkt;
  for (int j = s + t; j < e; j += 256) {
    int2 epk = tmp[j];
    int rl = epk.x >> 19;
    int k = atomicAdd(&rank[rl], 1);
    int dst = rowptr[b * kRowsPerBkt + rl] + coff[rl] + k;
    edges[dst] = make_int2(epk.x & 0x7FFFF, epk.y);
  }
}

// --- layer-3 pruning: mark rows read by the accumulators, then build a
// degree-BINNED compact list (subset gathers are random anyway, so binning
// costs no edge locality but kills the 1.38x wave-max padding).
__global__ void mark_rows(const int* __restrict__ users, const int* __restrict__ items,
                          int* __restrict__ mark) {
  int i = blockIdx.x * blockDim.x + threadIdx.x;
  if (i >= kB) return;
  mark[users[i]] = 1;
  mark[kUsers + items[i]] = 1;
}

__global__ void sub_hist(const int* __restrict__ rowptr, const int* __restrict__ mark,
                         int* __restrict__ dh) {
  __shared__ int h[64];
  int t = threadIdx.x;
  if (t < 64) h[t] = 0;
  __syncthreads();
  int i = blockIdx.x * 256 + t;
  if (i < kN && mark[i]) {
    int d = min(rowptr[i + 1] - rowptr[i], 63);
    atomicAdd(&h[d], 1);
  }
  __syncthreads();
  if (t < 64 && h[t]) atomicAdd(&dh[t], h[t]);
}

__global__ void deg_scan(int* __restrict__ dh, int* __restrict__ scnt) {  // 64 thr
  int t = threadIdx.x;
  int v = dh[t];
  int x = v;
  for (int o = 1; o < 64; o <<= 1) {
    int y = __shfl_up(x, o, 64);
    if (t >= o) x += y;
  }
  if (t == 63) *scnt = x;
  dh[t] = x - v;   // exclusive bin base
}

__global__ void sub_place(const int* __restrict__ rowptr, const int* __restrict__ mark,
                          int* __restrict__ dh, int* __restrict__ list) {
  __shared__ int h[64], base[64];
  int t = threadIdx.x;
  if (t < 64) h[t] = 0;
  __syncthreads();
  int i = blockIdx.x * 256 + t;
  int d = 0, lr = 0;
  bool okv = (i < kN) && mark[i];
  if (okv) {
    d = min(rowptr[i + 1] - rowptr[i], 63);
    lr = atomicAdd(&h[d], 1);
  }
  __syncthreads();
  if (t < 64) base[t] = h[t] ? atomicAdd(&dh[t], h[t]) : 0;
  __syncthreads();
  if (okv) list[base[d] + lr] = i;
}

// Convert concat(uemb, iemb) to fp8 e4m3, stored = 64*true. One thread per 8
// elems (one v2i out). nt loads: fp32 embeddings never re-read in bulk.
__global__ void to_fp8(const float* __restrict__ ue, const float* __restrict__ ie,
                       unsigned char* __restrict__ xq) {
  int t = blockIdx.x * blockDim.x + threadIdx.x;
  if (t >= kN * kD / 8) return;
  int row = t >> 3;
  int seg = t & 7;
  const float* src = (row < kUsers) ? (ue + (size_t)row * kD + seg * 8)
                                    : (ie + (size_t)(row - kUsers) * kD + seg * 8);
  v4f a = __builtin_nontemporal_load((const v4f*)src);
  v4f b = __builtin_nontemporal_load((const v4f*)src + 1);
  float f[8] = {a.x, a.y, a.z, a.w, b.x, b.y, b.z, b.w};
  unsigned int w0 = 0, w1 = 0;
#pragma unroll
  for (int k = 0; k < 4; ++k) w0 |= (unsigned int)enc(f[k] * 64.f) << (8 * k);
#pragma unroll
  for (int k = 0; k < 4; ++k) w1 |= (unsigned int)enc(f[4 + k] * 64.f) << (8 * k);
  v2i o; o.x = (int)w0; o.y = (int)w1;
  ((v2i*)xq)[t] = o;
}

// Reduction-free spmm, fp8 in / fp8 out (both scaled 64*true). One 8-lane
// group per row; lane l owns dims [8l,8l+8) = one 8-byte gather (row = one
// 64 B line). Unroll-4 edge prefetch. acc = sum v*(stored) with v
// premultiplied by 256 (decode yields stored/256), so acc = 64*true_y ->
// stored directly. Identity row order: wave's 8 edge segments contiguous
// (round-2 lesson: degree-perm scattered them, +25 MB fetch).
template <bool SUBSET>
__global__ __launch_bounds__(256, 8) void spmm(
    const int* __restrict__ rowptr, const int2* __restrict__ edges,
    const unsigned char* __restrict__ x, unsigned char* __restrict__ yq,
    const int* __restrict__ list, const int* __restrict__ cnt) {
  int t = threadIdx.x;
  int l = t & 7;                               // dim octet
  int wid = (blockIdx.x * 256 + t) >> 6;       // global wave id
  int g = (t >> 3) & 7;                        // group (row) within wave
  int p = wid * 8 + g;
  int r = -1;
  if (SUBSET) {
    int n = *cnt;
    if (p < n) r = list[p];
  } else {
    if (p < kN) r = p;
  }
  int s = 0, e = 0;
  if (r >= 0) { s = rowptr[r]; e = rowptr[r + 1]; }
  int mx = e - s;
#pragma unroll
  for (int m = 8; m <= 32; m <<= 1) mx = max(mx, __shfl_xor(mx, m, 64));
  float acc[8];
#pragma unroll
  for (int k = 0; k < 8; ++k) acc[k] = 0.f;
  int last = max(e - 1, 0);
  int j = s;
  int2 E0 = edges[min(j, last)];
  int2 E1 = edges[min(j + 1, last)];
  int2 E2 = edges[min(j + 2, last)];
  int2 E3 = edges[min(j + 3, last)];
  for (int it = 0; it < mx; it += 4) {
    float v0 = (j     < e) ? __int_as_float(E0.y) * 256.f : 0.f;
    float v1 = (j + 1 < e) ? __int_as_float(E1.y) * 256.f : 0.f;
    float v2 = (j + 2 < e) ? __int_as_float(E2.y) * 256.f : 0.f;
    float v3 = (j + 3 < e) ? __int_as_float(E3.y) * 256.f : 0.f;
    v2i h0 = ((const v2i*)(x + (size_t)E0.x * kD))[l];
    v2i h1 = ((const v2i*)(x + (size_t)E1.x * kD))[l];
    v2i h2 = ((const v2i*)(x + (size_t)E2.x * kD))[l];
    v2i h3 = ((const v2i*)(x + (size_t)E3.x * kD))[l];
    j += 4;
    E0 = edges[min(j, last)];                  // prefetch next quad (clamped)
    E1 = edges[min(j + 1, last)];
    E2 = edges[min(j + 2, last)];
    E3 = edges[min(j + 3, last)];
    float f0, f1, f2, f3;
    dec4((unsigned int)h0.x, f0, f1, f2, f3);
    acc[0] = fmaf(v0, f0, acc[0]); acc[1] = fmaf(v0, f1, acc[1]);
    acc[2] = fmaf(v0, f2, acc[2]); acc[3] = fmaf(v0, f3, acc[3]);
    dec4((unsigned int)h0.y, f0, f1, f2, f3);
    acc[4] = fmaf(v0, f0, acc[4]); acc[5] = fmaf(v0, f1, acc[5]);
    acc[6] = fmaf(v0, f2, acc[6]); acc[7] = fmaf(v0, f3, acc[7]);
    dec4((unsigned int)h1.x, f0, f1, f2, f3);
    acc[0] = fmaf(v1, f0, acc[0]); acc[1] = fmaf(v1, f1, acc[1]);
    acc[2] = fmaf(v1, f2, acc[2]); acc[3] = fmaf(v1, f3, acc[3]);
    dec4((unsigned int)h1.y, f0, f1, f2, f3);
    acc[4] = fmaf(v1, f0, acc[4]); acc[5] = fmaf(v1, f1, acc[5]);
    acc[6] = fmaf(v1, f2, acc[6]); acc[7] = fmaf(v1, f3, acc[7]);
    dec4((unsigned int)h2.x, f0, f1, f2, f3);
    acc[0] = fmaf(v2, f0, acc[0]); acc[1] = fmaf(v2, f1, acc[1]);
    acc[2] = fmaf(v2, f2, acc[2]); acc[3] = fmaf(v2, f3, acc[3]);
    dec4((unsigned int)h2.y, f0, f1, f2, f3);
    acc[4] = fmaf(v2, f0, acc[4]); acc[5] = fmaf(v2, f1, acc[5]);
    acc[6] = fmaf(v2, f2, acc[6]); acc[7] = fmaf(v2, f3, acc[7]);
    dec4((unsigned int)h3.x, f0, f1, f2, f3);
    acc[0] = fmaf(v3, f0, acc[0]); acc[1] = fmaf(v3, f1, acc[1]);
    acc[2] = fmaf(v3, f2, acc[2]); acc[3] = fmaf(v3, f3, acc[3]);
    dec4((unsigned int)h3.y, f0, f1, f2, f3);
    acc[4] = fmaf(v3, f0, acc[4]); acc[5] = fmaf(v3, f1, acc[5]);
    acc[6] = fmaf(v3, f2, acc[6]); acc[7] = fmaf(v3, f3, acc[7]);
  }
  if (r >= 0) {
    unsigned int w0 = 0, w1 = 0;
#pragma unroll
    for (int k = 0; k < 4; ++k) w0 |= (unsigned int)enc(acc[k]) << (8 * k);
#pragma unroll
    for (int k = 0; k < 4; ++k) w1 |= (unsigned int)enc(acc[4 + k]) << (8 * k);
    v2i o; o.x = (int)w0; o.y = (int)w1;
    ((v2i*)yq)[(size_t)r * 8 + l] = o;
  }
}

// acc = emb_gather + layer1 (fp8 layer output, stored = 64*true -> dec1x4)
__global__ void acc_add_init(const int* __restrict__ users, const int* __restrict__ items,
                             const float* __restrict__ uemb, const float* __restrict__ iemb,
                             const unsigned char* __restrict__ xq, float* __restrict__ uacc,
                             float* __restrict__ iacc) {
  int tid = blockIdx.x * blockDim.x + threadIdx.x;
  if (tid >= kB * kD) return;
  int b = tid >> 6, d = tid & 63;
  int u = users[b], iw = items[b];
  uacc[tid] = uemb[(size_t)u * kD + d] + dec1x4(xq[(size_t)u * kD + d]);
  iacc[tid] = iemb[(size_t)iw * kD + d] + dec1x4(xq[(size_t)(kUsers + iw) * kD + d]);
}

__global__ void acc_add(const int* __restrict__ users, const int* __restrict__ items,
                        const unsigned char* __restrict__ xq, float* __restrict__ uacc,
                        float* __restrict__ iacc) {
  int tid = blockIdx.x * blockDim.x + threadIdx.x;
  if (tid >= kB * kD) return;
  int b = tid >> 6, d = tid & 63;
  uacc[tid] += dec1x4(xq[(size_t)users[b] * kD + d]);
  iacc[tid] += dec1x4(xq[(size_t)(kUsers + items[b]) * kD + d]);
}

// layer-3 accumulate + dot + scale, fused
__global__ void acc_add_fin(const int* __restrict__ users, const int* __restrict__ items,
                            const unsigned char* __restrict__ xq, const float* __restrict__ uacc,
                            const float* __restrict__ iacc, float* __restrict__ out) {
  int tid = blockIdx.x * blockDim.x + threadIdx.x;
  if (tid >= kB * kD) return;
  int b = tid >> 6, d = tid & 63;
  float u = uacc[tid] + dec1x4(xq[(size_t)users[b] * kD + d]);
  float v = iacc[tid] + dec1x4(xq[(size_t)(kUsers + items[b]) * kD + d]);
  float p = u * v;
  for (int o = 32; o > 0; o >>= 1) p += __shfl_down(p, o, 64);
  if (d == 0) out[b] = p * 0.0625f;
}

}  // namespace

extern "C" void kernel_launch(void* const* d_in, const int* in_sizes, int n_in,
                              void* d_out, int out_size, void* d_ws, size_t ws_size,
                              hipStream_t stream) {
  const int*   users = (const int*)d_in[0];
  const int*   items = (const int*)d_in[1];
  const int*   erow  = (const int*)d_in[2];
  const int*   ecol  = (const int*)d_in[3];
  const float* evals = (const float*)d_in[4];
  const float* uemb  = (const float*)d_in[5];
  const float* iemb  = (const float*)d_in[6];
  float* out = (float*)d_out;

  char* ws = (char*)d_ws;
  size_t off = 0;
  auto take = [&](size_t bytes) -> char* {
    char* p = ws + off;
    off = (off + bytes + 255) & ~(size_t)255;
    return p;
  };
  int*    rowptr   = (int*)take((size_t)(kN + 1) * 4);
  int*    gpos     = (int*)take((kNBKT + 1) * 4);
  int*    partials = (int*)take(256 * 4);
  int*    mark     = (int*)take((size_t)kN * 4);
  int*    list     = (int*)take((size_t)kMaxSub * 4);
  int*    scnt     = (int*)take(256);
  int2*   edges    = (int2*)take((size_t)kNNZ * 8);
  int2*   tmp      = (int2*)take((size_t)kNBKT * kCap * 8);      // 48.2 MB
  unsigned char* xq0 = (unsigned char*)take((size_t)kN * kD);    // fp8 ping (19.2 MB)
  unsigned char* xq1 = (unsigned char*)take((size_t)kN * kD);    // fp8 pong
  float*  uacc     = (float*)take((size_t)kB * kD * 4);
  float*  iacc     = (float*)take((size_t)kB * kD * 4);
  int*    ctab     = (int*)xq0;   // 6.0 MB, dead before to_fp8 writes xq0
  int*    dh       = partials;    // partials dead after scan3
  (void)ws_size; (void)in_sizes; (void)n_in; (void)out_size;

  const int nScatBlocks = (kNNZ + kSEPB - 1) / kSEPB;  // 1221
  const int nSpmmBlocks = (kN + 31) / 32;              // 8 rows/wave, 4 waves/block
  const int nSubBlocks  = (kMaxSub + 31) / 32;         // 1024
  const int nRowBlocks  = (kN + 255) / 256;            // 1172

  // --- CSR build: fixed-capacity bucket sort, then parallel counting sort ---
  zero_i32<<<1, 256, 0, stream>>>(gpos, kNBKT + 1);
  zero_i32<<<nRowBlocks, 256, 0, stream>>>(mark, kN);
  bucket_scatter<<<nScatBlocks, 256, 0, stream>>>(erow, ecol, evals, gpos, tmp);
  chunk_hist<<<kNBKT * kMC, 256, 0, stream>>>(gpos, tmp, ctab);
  scanA<<<kNBKT, 256, 0, stream>>>(ctab, rowptr, partials);
  scan2<<<1, 256, 0, stream>>>(partials);
  scan3<<<(kN + 1 + 255) / 256, 256, 0, stream>>>(rowptr, partials);
  chunk_place<<<kNBKT * kMC, 256, 0, stream>>>(gpos, tmp, rowptr, ctab, edges);

  // --- layer-3 row subset, degree-binned (dh aliases partials, dead now) ---
  mark_rows<<<(kB + 255) / 256, 256, 0, stream>>>(users, items, mark);
  zero_i32<<<1, 64, 0, stream>>>(dh, 64);
  sub_hist<<<nRowBlocks, 256, 0, stream>>>(rowptr, mark, dh);
  deg_scan<<<1, 64, 0, stream>>>(dh, scnt);
  sub_place<<<nRowBlocks, 256, 0, stream>>>(rowptr, mark, dh, list);

  // --- fp8 copy of concat embeddings (after chunk_place: ctab aliases xq0) ---
  to_fp8<<<(kN * kD / 8 + 255) / 256, 256, 0, stream>>>(uemb, iemb, xq0);
  // --- 3 propagation layers; fp8 ping-pong; layer 3 pruned to subset ---
  spmm<false><<<nSpmmBlocks, 256, 0, stream>>>(rowptr, edges, xq0, xq1, nullptr, nullptr);
  acc_add_init<<<(kB * kD) / 256, 256, 0, stream>>>(users, items, uemb, iemb, xq1, uacc, iacc);
  spmm<false><<<nSpmmBlocks, 256, 0, stream>>>(rowptr, edges, xq1, xq0, nullptr, nullptr);
  acc_add<<<(kB * kD) / 256, 256, 0, stream>>>(users, items, xq0, uacc, iacc);
  spmm<true ><<<nSubBlocks, 256, 0, stream>>>(rowptr, edges, xq0, xq1, list, scnt);
  acc_add_fin<<<(kB * kD) / 256, 256, 0, stream>>>(users, items, xq1, uacc, iacc, out);
}

// Round 6
// 521.511 us; speedup vs baseline: 1.4103x; 1.0419x over previous
//
#include <hip/hip_runtime.h>
#include <hip/hip_fp16.h>
#include <hip/hip_fp8.h>

namespace {

constexpr int kUsers = 100000;
constexpr int kItems = 200000;
constexpr int kN     = kUsers + kItems;   // 300000
constexpr int kD     = 64;
constexpr int kNNZ   = 5000000;
constexpr int kB     = 16384;
constexpr int kRowsPerBkt = 2048;                       // rows per coarse bucket
constexpr int kNBKT  = (kN + kRowsPerBkt - 1) / kRowsPerBkt;  // 147
constexpr int kSEPB  = 4096;                            // edges per bucket_scatter block
constexpr int kCE    = 8192;                            // edges per finalize chunk
constexpr int kMC    = 5;                               // chunks per bucket
constexpr int kCap   = kMC * kCE;                       // 40960 slots/bucket (mean 34133, sd 185)
constexpr int kMaxSub = 2 * kB;                         // upper bound on marked rows

typedef int   v2i __attribute__((ext_vector_type(2)));
typedef float v4f __attribute__((ext_vector_type(4)));

// --- fp8 e4m3 storage: buffers hold 64*true_value (keeps x in e4m3 normal
// range). Decode: native v_cvt_pk_f32_fp8 where available (2 ops/word vs ~8
// for the bit-trick) -> round-3 post-mortem showed decode VALU (71% busy) was
// throttling the fetch pipe. Bit-trick fallback yields stored/256, patched by
// kValScale on the edge weight. NOTE: the builtins return a PLAIN float
// vector (vector_size attr), no .x/.y members -> index with [].
#if defined(__has_builtin)
#if __has_builtin(__builtin_amdgcn_cvt_pk_f32_fp8) && __has_builtin(__builtin_amdgcn_cvt_f32_fp8)
#define NATIVE_FP8 1
#endif
#endif
#ifndef NATIVE_FP8
#define NATIVE_FP8 0
#endif

constexpr float kValScale = NATIVE_FP8 ? 1.0f : 256.0f;

__device__ inline void dec8(v2i h, float* f) {
#if NATIVE_FP8
  auto a0 = __builtin_amdgcn_cvt_pk_f32_fp8(h.x, false);
  auto a1 = __builtin_amdgcn_cvt_pk_f32_fp8(h.x, true);
  auto a2 = __builtin_amdgcn_cvt_pk_f32_fp8(h.y, false);
  auto a3 = __builtin_amdgcn_cvt_pk_f32_fp8(h.y, true);
  f[0] = a0[0]; f[1] = a0[1]; f[2] = a1[0]; f[3] = a1[1];
  f[4] = a2[0]; f[5] = a2[1]; f[6] = a3[0]; f[7] = a3[1];
#else
  unsigned int ws[2] = {(unsigned int)h.x, (unsigned int)h.y};
#pragma unroll
  for (int q = 0; q < 2; ++q) {
    unsigned int w = ws[q];
    unsigned int a = ((w & 0x007f007fu) << 7) | ((w & 0x00800080u) << 8);
    unsigned int b = (((w >> 8) & 0x007f007fu) << 7) | (((w >> 8) & 0x00800080u) << 8);
    float2 e = __half22float2(*reinterpret_cast<const __half2*>(&a));
    float2 o = __half22float2(*reinterpret_cast<const __half2*>(&b));
    f[4 * q + 0] = e.x; f[4 * q + 1] = o.x; f[4 * q + 2] = e.y; f[4 * q + 3] = o.y;
  }
#endif
}

__device__ inline float dec1(unsigned char b) {  // stored(=64*true) -> true
#if NATIVE_FP8
  return __builtin_amdgcn_cvt_f32_fp8((int)b, 0) * 0.015625f;
#else
  unsigned int hb = ((b & 0x7fu) << 7) | ((b & 0x80u) << 8);
  return __half2float(__ushort_as_half((unsigned short)hb)) * 4.0f;
#endif
}

__device__ inline unsigned char enc(float f) { __hip_fp8_e4m3 q(f); return q.__x; }

// packed edge: bits[18:0] = col, bits[31:19] = val13 (fp16 bits rounded to
// 5-exp + 8-mantissa; vals are >= 0 so no sign bit). rel err 2^-9, negligible
// vs fp8's 2^-4.
__device__ inline float vdec(int w) {
  return __half2float(__ushort_as_half((unsigned short)((w >> 17) & 0x7FFC))) * kValScale;
}

__global__ void zero3(int* __restrict__ gpos, int* __restrict__ mark,
                      int* __restrict__ dh, int* __restrict__ scnt) {
  int i = blockIdx.x * blockDim.x + threadIdx.x;
  if (i < kN) mark[i] = 0;
  if (i < kNBKT + 1) gpos[i] = 0;
  if (i < 64) dh[i] = 0;   // dh is a DEDICATED buffer (round-5 post-mortem:
                           // aliasing partials here caused OOB -> abort)
  if (i == 0) scnt[0] = 0;
}

// Counting-sort partition of 4096 edges into 147 coarse buckets; per-wave LDS
// histograms (4x147) cut same-address atomic serialization 4x. LDS staging so
// tmp writes go out in coalesced bucket-run bursts. tmp is read twice later ->
// plain stores (L2/L3-resident); only the read-once input streams are nt.
// tmp.x = rowlocal<<19|col (for hist/place), tmp.y = packed col|val13 (final
// edge payload, copied verbatim by chunk_place).
__global__ void bucket_scatter(const int* __restrict__ row, const int* __restrict__ col,
                               const float* __restrict__ val, int* __restrict__ gpos,
                               int2* __restrict__ tmp) {
  __shared__ int hcnt[4][kNBKT];   // per-wave counts -> wave-exclusive offsets
  __shared__ int lofs[kNBKT];
  __shared__ int hbase[kNBKT];
  __shared__ int lds[256];
  __shared__ int2 se[kSEPB];
  __shared__ unsigned short sb[kSEPB];
  int t = threadIdx.x;
  int wv = t >> 6;
  long base = (long)blockIdx.x * kSEPB;
  int valid = (int)min((long)kSEPB, (long)kNNZ - base);
  for (int i = t; i < kNBKT; i += 256) {
    hcnt[0][i] = 0; hcnt[1][i] = 0; hcnt[2][i] = 0; hcnt[3][i] = 0;
  }
  __syncthreads();
  int pk[16], py[16], bk[16], rk[16];
  bool ok[16];
#pragma unroll
  for (int j = 0; j < 16; ++j) {
    long i = base + j * 256 + t;
    ok[j] = (i < kNNZ);
    if (ok[j]) {
      int r = __builtin_nontemporal_load(row + i);
      int c = __builtin_nontemporal_load(col + i);
      float v = __builtin_nontemporal_load(val + i);
      bk[j] = r >> 11;
      pk[j] = ((r & 2047) << 19) | c;
      unsigned short hb = __half_as_ushort(__float2half_rn(v));
      int v13 = ((int)hb + 2) >> 2;              // round to exp5+man8
      py[j] = c | (v13 << 19);
      rk[j] = atomicAdd(&hcnt[wv][bk[j]], 1);
    }
  }
  __syncthreads();
  int own = 0;
  if (t < kNBKT) {
    int c0 = hcnt[0][t], c1 = hcnt[1][t], c2 = hcnt[2][t], c3 = hcnt[3][t];
    hcnt[0][t] = 0; hcnt[1][t] = c0; hcnt[2][t] = c0 + c1; hcnt[3][t] = c0 + c1 + c2;
    own = c0 + c1 + c2 + c3;
  }
  lds[t] = own;
  __syncthreads();
  for (int o = 1; o < 256; o <<= 1) {
    int x = (t >= o) ? lds[t - o] : 0;
    __syncthreads();
    if (t >= o) lds[t] += x;
    __syncthreads();
  }
  if (t < kNBKT) {
    lofs[t] = lds[t] - own;
    hbase[t] = t * kCap + atomicAdd(&gpos[t], own);
  }
  __syncthreads();
#pragma unroll
  for (int j = 0; j < 16; ++j) {
    if (ok[j]) {
      int pos = lofs[bk[j]] + hcnt[wv][bk[j]] + rk[j];
      se[pos] = make_int2(pk[j], py[j]);
      sb[pos] = (unsigned short)bk[j];
    }
  }
  __syncthreads();
#pragma unroll
  for (int j = 0; j < 16; ++j) {
    int pos = t + j * 256;
    if (pos < valid) {
      int b = sb[pos];
      tmp[hbase[b] + (pos - lofs[b])] = se[pos];
    }
  }
}

// Grid = kNBKT*kMC. Per-(bucket,chunk) 2048-row LDS histogram -> ctab.
__global__ void chunk_hist(const int* __restrict__ gpos, const int2* __restrict__ tmp,
                           int* __restrict__ ctab) {
  __shared__ int h[kRowsPerBkt];
  int b = blockIdx.x / kMC, c = blockIdx.x % kMC;
  int t = threadIdx.x;
  for (int i = t; i < kRowsPerBkt; i += 256) h[i] = 0;
  __syncthreads();
  int s = b * kCap + c * kCE;
  int e = b * kCap + gpos[b];
  if (s + kCE < e) e = s + kCE;
  for (int j = s + t; j < e; j += 256) atomicAdd(&h[tmp[j].x >> 19], 1);
  __syncthreads();
  int* dst = ctab + (size_t)blockIdx.x * kRowsPerBkt;
  for (int i = t; i < kRowsPerBkt; i += 256) dst[i] = h[i];
}

__global__ void scanA(int* __restrict__ ctab, int* __restrict__ rowptr,
                      int* __restrict__ partials) {
  __shared__ int lsum[256];
  int b = blockIdx.x, t = threadIdx.x;
  int cnt[8];
#pragma unroll
  for (int k = 0; k < 8; ++k) cnt[k] = 0;
  for (int c = 0; c < kMC; ++c) {
    int* p = ctab + (size_t)(b * kMC + c) * kRowsPerBkt;
#pragma unroll
    for (int k = 0; k < 8; ++k) {
      int idx = t * 8 + k;
      int v = p[idx];
      p[idx] = cnt[k];
      cnt[k] += v;
    }
  }
  int s = 0, pref[8];
#pragma unroll
  for (int k = 0; k < 8; ++k) { pref[k] = s; s += cnt[k]; }
  lsum[t] = s;
  __syncthreads();
  for (int o = 1; o < 256; o <<= 1) {
    int v = (t >= o) ? lsum[t - o] : 0;
    __syncthreads();
    if (t >= o) lsum[t] += v;
    __syncthreads();
  }
  int ex = (t == 0) ? 0 : lsum[t - 1];
#pragma unroll
  for (int k = 0; k < 8; ++k) {
    int r = b * kRowsPerBkt + t * 8 + k;
    if (r < kN) rowptr[r] = ex + pref[k];
  }
  if (t == 255) partials[b] = lsum[255];
}

__global__ void scan2(int* __restrict__ partials) {
  __shared__ int lds[256];
  int t = threadIdx.x;
  lds[t] = (t < kNBKT) ? partials[t] : 0;
  __syncthreads();
  for (int o = 1; o < 256; o <<= 1) {
    int v = (t >= o) ? lds[t - o] : 0;
    __syncthreads();
    if (t >= o) lds[t] += v;
    __syncthreads();
  }
  int ex = (t == 0) ? 0 : lds[t - 1];
  if (t < kNBKT) partials[t] = ex;
}

__global__ void scan3(int* __restrict__ rowptr, const int* __restrict__ partials) {
  int i = blockIdx.x * blockDim.x + threadIdx.x;
  if (i < kN) rowptr[i] += partials[i >> 11];
  else if (i == kN) rowptr[kN] = kNNZ;
}

// Grid = kNBKT*kMC. Place edges to final CSR slots; random 4B writes confined
// to the bucket's ~136 KB window.
__global__ void chunk_place(const int* __restrict__ gpos, const int2* __restrict__ tmp,
                            const int* __restrict__ rowptr, const int* __restrict__ ctab,
                            int* __restrict__ edges) {
  __shared__ int rank[kRowsPerBkt];
  int b = blockIdx.x / kMC, c = blockIdx.x % kMC;
  int t = threadIdx.x;
  for (int i = t; i < kRowsPerBkt; i += 256) rank[i] = 0;
  __syncthreads();
  int s = b * kCap + c * kCE;
  int e = b * kCap + gpos[b];
  if (s + kCE < e) e = s + kCE;
  const int* coff = ctab + (size_t)blockIdx.x * kRowsPerBkt;
  for (int j = s + t; j < e; j += 256) {
    int2 epk = tmp[j];
    int rl = epk.x >> 19;
    int k = atomicAdd(&rank[rl], 1);
    int dst = rowptr[b * kRowsPerBkt + rl] + coff[rl] + k;
    edges[dst] = epk.y;
  }
}

// --- layer-3 pruning: mark rows read by the accumulators, degree-binned list.
__global__ void mark_rows(const int* __restrict__ users, const int* __restrict__ items,
                          int* __restrict__ mark) {
  int i = blockIdx.x * blockDim.x + threadIdx.x;
  if (i >= kB) return;
  mark[users[i]] = 1;
  mark[kUsers + items[i]] = 1;
}

__global__ void sub_hist(const int* __restrict__ rowptr, const int* __restrict__ mark,
                         int* __restrict__ dh) {
  __shared__ int h[64];
  int t = threadIdx.x;
  if (t < 64) h[t] = 0;
  __syncthreads();
  int i = blockIdx.x * 256 + t;
  if (i < kN && mark[i]) {
    int d = min(rowptr[i + 1] - rowptr[i], 63);
    atomicAdd(&h[d], 1);
  }
  __syncthreads();
  if (t < 64 && h[t]) atomicAdd(&dh[t], h[t]);
}

__global__ void deg_scan(int* __restrict__ dh, int* __restrict__ scnt) {  // 64 thr
  int t = threadIdx.x;
  int v = dh[t];
  int x = v;
  for (int o = 1; o < 64; o <<= 1) {
    int y = __shfl_up(x, o, 64);
    if (t >= o) x += y;
  }
  if (t == 63) *scnt = x;
  dh[t] = x - v;   // exclusive bin base
}

__global__ void sub_place(const int* __restrict__ rowptr, const int* __restrict__ mark,
                          int* __restrict__ dh, int* __restrict__ list) {
  __shared__ int h[64], base[64];
  int t = threadIdx.x;
  if (t < 64) h[t] = 0;
  __syncthreads();
  int i = blockIdx.x * 256 + t;
  int d = 0, lr = 0;
  bool okv = (i < kN) && mark[i];
  if (okv) {
    d = min(rowptr[i + 1] - rowptr[i], 63);
    lr = atomicAdd(&h[d], 1);
  }
  __syncthreads();
  if (t < 64) base[t] = h[t] ? atomicAdd(&dh[t], h[t]) : 0;
  __syncthreads();
  if (okv) list[base[d] + lr] = i;
}

// Union the subset rows' edge endpoints into mark: layer-2 output is only
// consumed at subset rows (acc_add) and at cols of subset rows' edges (spmm
// layer 3) -> spmm layer 2 can skip ~16% of rows. One thread per subset row;
// list is degree-binned so waves have uniform trip counts.
__global__ void mark_cols(const int* __restrict__ list, const int* __restrict__ cnt,
                          const int* __restrict__ rowptr, const int* __restrict__ edges,
                          int* __restrict__ mark) {
  int p = blockIdx.x * blockDim.x + threadIdx.x;
  if (p >= *cnt) return;
  int r = list[p];
  int s = rowptr[r], e = rowptr[r + 1];
  for (int j = s; j < e; ++j) mark[edges[j] & 0x7FFFF] = 1;
}

// Convert concat(uemb, iemb) to fp8 e4m3, stored = 64*true. One thread per 8
// elems. nt loads: fp32 embeddings never re-read in bulk.
__global__ void to_fp8(const float* __restrict__ ue, const float* __restrict__ ie,
                       unsigned char* __restrict__ xq) {
  int t = blockIdx.x * blockDim.x + threadIdx.x;
  if (t >= kN * kD / 8) return;
  int row = t >> 3;
  int seg = t & 7;
  const float* src = (row < kUsers) ? (ue + (size_t)row * kD + seg * 8)
                                    : (ie + (size_t)(row - kUsers) * kD + seg * 8);
  v4f a = __builtin_nontemporal_load((const v4f*)src);
  v4f b = __builtin_nontemporal_load((const v4f*)src + 1);
  float f[8] = {a.x, a.y, a.z, a.w, b.x, b.y, b.z, b.w};
  unsigned int w0 = 0, w1 = 0;
#pragma unroll
  for (int k = 0; k < 4; ++k) w0 |= (unsigned int)enc(f[k] * 64.f) << (8 * k);
#pragma unroll
  for (int k = 0; k < 4; ++k) w1 |= (unsigned int)enc(f[4 + k] * 64.f) << (8 * k);
  v2i o; o.x = (int)w0; o.y = (int)w1;
  ((v2i*)xq)[t] = o;
}

// Reduction-free spmm, fp8 in / fp8 out (both scaled 64*true). One 8-lane
// group per row; lane l owns dims [8l,8l+8) = one 8-byte gather. Unroll-4
// edge prefetch. MODE 0: all rows. MODE 1: rows with aux[r]!=0 (others
// skipped: no edge/x fetch, no store). MODE 2: rows from aux list (subset).
// Identity row order for 0/1: wave's 8 edge segments contiguous.
template <int MODE>
__global__ __launch_bounds__(256, 8) void spmm(
    const int* __restrict__ rowptr, const int* __restrict__ edges,
    const unsigned char* __restrict__ x, unsigned char* __restrict__ yq,
    const int* __restrict__ aux, const int* __restrict__ cnt) {
  int t = threadIdx.x;
  int l = t & 7;                               // dim octet
  int wid = (blockIdx.x * 256 + t) >> 6;       // global wave id
  int g = (t >> 3) & 7;                        // group (row) within wave
  int p = wid * 8 + g;
  int r = -1;
  bool live = false;
  if (MODE == 2) {
    int n = *cnt;
    if (p < n) { r = aux[p]; live = true; }
  } else {
    if (p < kN) { r = p; live = (MODE == 0) || (aux[r] != 0); }
  }
  int s = 0, e = 0;
  if (live) { s = rowptr[r]; e = rowptr[r + 1]; }
  int mx = e - s;
#pragma unroll
  for (int m = 8; m <= 32; m <<= 1) mx = max(mx, __shfl_xor(mx, m, 64));
  float acc[8];
#pragma unroll
  for (int k = 0; k < 8; ++k) acc[k] = 0.f;
  int last = max(e - 1, 0);
  int j = s;
  int E0 = edges[min(j, last)];
  int E1 = edges[min(j + 1, last)];
  int E2 = edges[min(j + 2, last)];
  int E3 = edges[min(j + 3, last)];
  for (int it = 0; it < mx; it += 4) {
    float v0 = (j     < e) ? vdec(E0) : 0.f;
    float v1 = (j + 1 < e) ? vdec(E1) : 0.f;
    float v2 = (j + 2 < e) ? vdec(E2) : 0.f;
    float v3 = (j + 3 < e) ? vdec(E3) : 0.f;
    v2i h0 = ((const v2i*)(x + (size_t)(E0 & 0x7FFFF) * kD))[l];
    v2i h1 = ((const v2i*)(x + (size_t)(E1 & 0x7FFFF) * kD))[l];
    v2i h2 = ((const v2i*)(x + (size_t)(E2 & 0x7FFFF) * kD))[l];
    v2i h3 = ((const v2i*)(x + (size_t)(E3 & 0x7FFFF) * kD))[l];
    j += 4;
    E0 = edges[min(j, last)];                  // prefetch next quad (clamped)
    E1 = edges[min(j + 1, last)];
    E2 = edges[min(j + 2, last)];
    E3 = edges[min(j + 3, last)];
    float f[8];
    dec8(h0, f);
#pragma unroll
    for (int k = 0; k < 8; ++k) acc[k] = fmaf(v0, f[k], acc[k]);
    dec8(h1, f);
#pragma unroll
    for (int k = 0; k < 8; ++k) acc[k] = fmaf(v1, f[k], acc[k]);
    dec8(h2, f);
#pragma unroll
    for (int k = 0; k < 8; ++k) acc[k] = fmaf(v2, f[k], acc[k]);
    dec8(h3, f);
#pragma unroll
    for (int k = 0; k < 8; ++k) acc[k] = fmaf(v3, f[k], acc[k]);
  }
  if (live) {
    unsigned int w0 = 0, w1 = 0;
#pragma unroll
    for (int k = 0; k < 4; ++k) w0 |= (unsigned int)enc(acc[k]) << (8 * k);
#pragma unroll
    for (int k = 0; k < 4; ++k) w1 |= (unsigned int)enc(acc[4 + k]) << (8 * k);
    v2i o; o.x = (int)w0; o.y = (int)w1;
    ((v2i*)yq)[(size_t)r * 8 + l] = o;
  }
}

// acc = emb_gather + layer1 (fp8 layer output, stored = 64*true -> dec1)
__global__ void acc_add_init(const int* __restrict__ users, const int* __restrict__ items,
                             const float* __restrict__ uemb, const float* __restrict__ iemb,
                             const unsigned char* __restrict__ xq, float* __restrict__ uacc,
                             float* __restrict__ iacc) {
  int tid = blockIdx.x * blockDim.x + threadIdx.x;
  if (tid >= kB * kD) return;
  int b = tid >> 6, d = tid & 63;
  int u = users[b], iw = items[b];
  uacc[tid] = uemb[(size_t)u * kD + d] + dec1(xq[(size_t)u * kD + d]);
  iacc[tid] = iemb[(size_t)iw * kD + d] + dec1(xq[(size_t)(kUsers + iw) * kD + d]);
}

__global__ void acc_add(const int* __restrict__ users, const int* __restrict__ items,
                        const unsigned char* __restrict__ xq, float* __restrict__ uacc,
                        float* __restrict__ iacc) {
  int tid = blockIdx.x * blockDim.x + threadIdx.x;
  if (tid >= kB * kD) return;
  int b = tid >> 6, d = tid & 63;
  uacc[tid] += dec1(xq[(size_t)users[b] * kD + d]);
  iacc[tid] += dec1(xq[(size_t)(kUsers + items[b]) * kD + d]);
}

// layer-3 accumulate + dot + scale, fused
__global__ void acc_add_fin(const int* __restrict__ users, const int* __restrict__ items,
                            const unsigned char* __restrict__ xq, const float* __restrict__ uacc,
                            const float* __restrict__ iacc, float* __restrict__ out) {
  int tid = blockIdx.x * blockDim.x + threadIdx.x;
  if (tid >= kB * kD) return;
  int b = tid >> 6, d = tid & 63;
  float u = uacc[tid] + dec1(xq[(size_t)users[b] * kD + d]);
  float v = iacc[tid] + dec1(xq[(size_t)(kUsers + items[b]) * kD + d]);
  float p = u * v;
  for (int o = 32; o > 0; o >>= 1) p += __shfl_down(p, o, 64);
  if (d == 0) out[b] = p * 0.0625f;
}

}  // namespace

extern "C" void kernel_launch(void* const* d_in, const int* in_sizes, int n_in,
                              void* d_out, int out_size, void* d_ws, size_t ws_size,
                              hipStream_t stream) {
  const int*   users = (const int*)d_in[0];
  const int*   items = (const int*)d_in[1];
  const int*   erow  = (const int*)d_in[2];
  const int*   ecol  = (const int*)d_in[3];
  const float* evals = (const float*)d_in[4];
  const float* uemb  = (const float*)d_in[5];
  const float* iemb  = (const float*)d_in[6];
  float* out = (float*)d_out;

  char* ws = (char*)d_ws;
  size_t off = 0;
  auto take = [&](size_t bytes) -> char* {
    char* p = ws + off;
    off = (off + bytes + 255) & ~(size_t)255;
    return p;
  };
  int*    rowptr   = (int*)take((size_t)(kN + 1) * 4);
  int*    gpos     = (int*)take((kNBKT + 1) * 4);
  int*    partials = (int*)take(256 * 4);
  int*    dh       = (int*)take(256 * 4);    // DEDICATED (round-5 fix: was
                                             // aliased to partials, which
                                             // scanA/scan2 overwrite later)
  int*    mark     = (int*)take((size_t)kN * 4);
  int*    list     = (int*)take((size_t)kMaxSub * 4);
  int*    scnt     = (int*)take(256);
  int*    edges    = (int*)take((size_t)kNNZ * 4);               // 20 MB packed
  int2*   tmp      = (int2*)take((size_t)kNBKT * kCap * 8);      // 48.2 MB
  unsigned char* xq0 = (unsigned char*)take((size_t)kN * kD);    // fp8 ping (19.2 MB)
  unsigned char* xq1 = (unsigned char*)take((size_t)kN * kD);    // fp8 pong
  float*  uacc     = (float*)take((size_t)kB * kD * 4);
  float*  iacc     = (float*)take((size_t)kB * kD * 4);
  int*    ctab     = (int*)xq0;   // 6.0 MB, dead before to_fp8 writes xq0
  (void)ws_size; (void)in_sizes; (void)n_in; (void)out_size;

  const int nScatBlocks = (kNNZ + kSEPB - 1) / kSEPB;  // 1221
  const int nSpmmBlocks = (kN + 31) / 32;              // 8 rows/wave, 4 waves/block
  const int nSubBlocks  = (kMaxSub + 31) / 32;         // 1024
  const int nRowBlocks  = (kN + 255) / 256;            // 1172

  // --- CSR build: fixed-capacity bucket sort, then parallel counting sort ---
  zero3<<<nRowBlocks, 256, 0, stream>>>(gpos, mark, dh, scnt);
  bucket_scatter<<<nScatBlocks, 256, 0, stream>>>(erow, ecol, evals, gpos, tmp);
  chunk_hist<<<kNBKT * kMC, 256, 0, stream>>>(gpos, tmp, ctab);
  scanA<<<kNBKT, 256, 0, stream>>>(ctab, rowptr, partials);
  scan2<<<1, 256, 0, stream>>>(partials);
  scan3<<<(kN + 1 + 255) / 256, 256, 0, stream>>>(rowptr, partials);
  chunk_place<<<kNBKT * kMC, 256, 0, stream>>>(gpos, tmp, rowptr, ctab, edges);

  // --- layer-3 row subset, degree-binned; then union its edge endpoints into
  //     mark for the layer-2 row mask ---
  mark_rows<<<(kB + 255) / 256, 256, 0, stream>>>(users, items, mark);
  sub_hist<<<nRowBlocks, 256, 0, stream>>>(rowptr, mark, dh);
  deg_scan<<<1, 64, 0, stream>>>(dh, scnt);
  sub_place<<<nRowBlocks, 256, 0, stream>>>(rowptr, mark, dh, list);
  mark_cols<<<(kMaxSub + 255) / 256, 256, 0, stream>>>(list, scnt, rowptr, edges, mark);

  // --- fp8 copy of concat embeddings (after chunk_place: ctab aliases xq0) ---
  to_fp8<<<(kN * kD / 8 + 255) / 256, 256, 0, stream>>>(uemb, iemb, xq0);
  // --- 3 propagation layers; fp8 ping-pong; layer 2 masked, layer 3 subset ---
  spmm<0><<<nSpmmBlocks, 256, 0, stream>>>(rowptr, edges, xq0, xq1, nullptr, nullptr);
  acc_add_init<<<(kB * kD) / 256, 256, 0, stream>>>(users, items, uemb, iemb, xq1, uacc, iacc);
  spmm<1><<<nSpmmBlocks, 256, 0, stream>>>(rowptr, edges, xq1, xq0, mark, nullptr);
  acc_add<<<(kB * kD) / 256, 256, 0, stream>>>(users, items, xq0, uacc, iacc);
  spmm<2><<<nSubBlocks, 256, 0, stream>>>(rowptr, edges, xq0, xq1, list, scnt);
  acc_add_fin<<<(kB * kD) / 256, 256, 0, stream>>>(users, items, xq1, uacc, iacc, out);
}